// Round 5
// baseline (3093.394 us; speedup 1.0000x reference)
//
#include <hip/hip_runtime.h>
#include <hip/hip_bf16.h>
#include <math.h>

// Problem constants
#define HID       300
#define HP        320
#define NH        4
#define E_BONDS   60000
#define NATOMS    30000
#define KNB       6
#define NMOLS     600
#define APM       50
#define AFD       144
#define BONDIN    158

typedef unsigned short u16;
typedef unsigned int   u32;
typedef _Float16 f16;
typedef f16   f16x8 __attribute__((ext_vector_type(8)));
typedef float f32x4 __attribute__((ext_vector_type(4)));

// ---------------- helpers ----------------
__device__ inline float hlo(u32 u) { union { u32 i; f16 h[2]; } c; c.i = u; return (float)c.h[0]; }
__device__ inline float hhi(u32 u) { union { u32 i; f16 h[2]; } c; c.i = u; return (float)c.h[1]; }
__device__ inline u32 packh2(float a, float b) {
    union { u32 i; f16 h[2]; } c; c.h[0] = (f16)a; c.h[1] = (f16)b; return c.i;
}

__device__ inline void gl2lds16(const void* g, void* l) {
    __builtin_amdgcn_global_load_lds(
        (const __attribute__((address_space(1))) void*)g,
        (__attribute__((address_space(3))) void*)l, 16, 0, 0);
}

// ---------------------------------------------------------------------------
// MFMA GEMM (unchanged from round 4): C = A[M][lda] @ B[Nb][ldb]^T, f16 in.
// EPI: 0 Cf=v | 1 Ch=h(v) | 2 Ch=h(v),out2=h(relu v) | 3 v+=resid,relu,Ch
//      4 v+=Cf+bias,relu,Cf&Ch | 5 v+=bias,relu,Cf
// ---------------------------------------------------------------------------
template <int BN, int EPI>
__global__ __launch_bounds__(256) void mfma_gemm_k(
    const f16* __restrict__ A, int lda,
    const f16* __restrict__ B, int ldb,
    int M, int Nb, int K, int ldc,
    float* __restrict__ Cf, f16* __restrict__ Ch,
    const float* __restrict__ bias,
    const f16* __restrict__ resid,
    f16* __restrict__ out2)
{
    constexpr int NF = BN / 32;
    __shared__ f16 sA[128 * 64];
    __shared__ f16 sB[BN * 64];
    const int tid  = threadIdx.x;
    const int lane = tid & 63;
    const int wv   = tid >> 6;
    const int wm   = wv >> 1, wn = wv & 1;
    const int m0   = blockIdx.x * 128, n0 = blockIdx.y * BN;

    f32x4 acc[4][NF];
#pragma unroll
    for (int i = 0; i < 4; ++i)
#pragma unroll
        for (int j = 0; j < NF; ++j) acc[i][j] = (f32x4){0.f, 0.f, 0.f, 0.f};

    for (int k0 = 0; k0 < K; k0 += 64) {
        __syncthreads();
#pragma unroll
        for (int i = 0; i < 4; ++i) {
            int o   = (((i * 4 + wv) * 64) + lane) * 16;
            int row = o >> 7;
            int p   = (o >> 4) & 7;
            int gr  = m0 + row; gr = gr < M ? gr : M - 1;
            const f16* g = A + (size_t)gr * lda + k0 + ((p ^ (row & 7)) << 3);
            gl2lds16(g, (char*)sA + (i * 4 + wv) * 1024);
        }
#pragma unroll
        for (int i = 0; i < BN / 32; ++i) {
            int o   = (((i * 4 + wv) * 64) + lane) * 16;
            int row = o >> 7;
            int p   = (o >> 4) & 7;
            int gr  = n0 + row; gr = gr < Nb ? gr : Nb - 1;
            const f16* g = B + (size_t)gr * ldb + k0 + ((p ^ (row & 7)) << 3);
            gl2lds16(g, (char*)sB + (i * 4 + wv) * 1024);
        }
        __syncthreads();

        const int rl = lane & 15, cl = lane >> 4;
#pragma unroll
        for (int kh = 0; kh < 2; ++kh) {
            f16x8 af[4], bfr[NF];
#pragma unroll
            for (int mf = 0; mf < 4; ++mf) {
                int row = wm * 64 + mf * 16 + rl;
                int ch  = (kh * 4 + cl) ^ (row & 7);
                af[mf]  = *(const f16x8*)&sA[row * 64 + ch * 8];
            }
#pragma unroll
            for (int nf = 0; nf < NF; ++nf) {
                int row = wn * (BN / 2) + nf * 16 + rl;
                int ch  = (kh * 4 + cl) ^ (row & 7);
                bfr[nf] = *(const f16x8*)&sB[row * 64 + ch * 8];
            }
#pragma unroll
            for (int mf = 0; mf < 4; ++mf)
#pragma unroll
                for (int nf = 0; nf < NF; ++nf)
                    acc[mf][nf] = __builtin_amdgcn_mfma_f32_16x16x32_f16(
                        af[mf], bfr[nf], acc[mf][nf], 0, 0, 0);
        }
    }

    const int rl = lane & 15, cl = lane >> 4;
#pragma unroll
    for (int mf = 0; mf < 4; ++mf) {
#pragma unroll
        for (int r = 0; r < 4; ++r) {
            int gm = m0 + wm * 64 + mf * 16 + cl * 4 + r;
            if (gm >= M) continue;
#pragma unroll
            for (int nf = 0; nf < NF; ++nf) {
                int gn = n0 + wn * (BN / 2) + nf * 16 + rl;
                if (gn >= ldc) continue;
                float v = acc[mf][nf][r];
                size_t ci = (size_t)gm * ldc + gn;
                if (EPI == 0) {
                    Cf[ci] = v;
                } else if (EPI == 1) {
                    Ch[ci] = (f16)v;
                } else if (EPI == 2) {
                    Ch[ci] = (f16)v;
                    out2[ci] = (f16)fmaxf(v, 0.f);
                } else if (EPI == 3) {
                    v += (float)resid[ci];
                    Ch[ci] = (f16)fmaxf(v, 0.f);
                } else if (EPI == 4) {
                    v += Cf[ci];
                    v += (gn < HID) ? bias[gn] : 0.f;
                    v = fmaxf(v, 0.f);
                    Cf[ci] = v; Ch[ci] = (f16)v;
                } else {
                    v += (gn < HID) ? bias[gn] : 0.f;
                    Cf[ci] = fmaxf(v, 0.f);
                }
            }
        }
    }
}

// ---------------------------------------------------------------------------
// FUSED message-passing iteration: one kernel does, per head:
//   GEMM1 (mt_n = msg_tile @ WmaT_n) -> sMC  ->  scores/softmax/comp (in-place
//   in sMC, nei rows held in registers across heads)  ->  GEMM2 partial
//   (acc2 += comp_n @ WhT2_n).  Epilogue: msg_out = relu(binput + acc2).
// mt/comp never touch global memory. Block = 64 bonds, 1024 thr = 16 waves
// (4m x 4n; wave tile 16 x 160 as 5 strided 16-col frags).
// ---------------------------------------------------------------------------
#define SMC_LD 328   // 320 + 8 pad: row stride 656B -> bank offset 4/row

__global__ __launch_bounds__(1024, 1) void fused_mp_k(
    const f16* __restrict__ msgIn,   // [E][320]
    f16* __restrict__ msgOut,        // [E][320]
    const f16* __restrict__ binh,    // [E][320]
    const int* __restrict__ bgraph,  // [E][6]
    const f16* __restrict__ WmaT,    // [4*320][320]  row n*320+d, col h
    const f16* __restrict__ WhT2)    // [4*320][320]  row n*320+h, col d
{
    __shared__ f16 sMsg[64 * 320];        // XOR-swizzled 16B chunks
    __shared__ f16 sMC[64 * SMC_LD];      // mt_n / comp_n (padded, no swizzle)
    __shared__ f16 sB[320 * 64];          // weight k-chunk (XOR-swizzled)

    const int tid  = threadIdx.x;
    const int lane = tid & 63;
    const int wv   = tid >> 6;            // 0..15
    const int wm   = wv >> 2;             // 0..3 (row group of 16 bonds)
    const int wn   = wv & 3;              // 0..3 (col frag base)
    const int rl   = lane & 15, cl = lane >> 4;
    const int e0   = blockIdx.x * 64;

    // ---- gather nei rows into registers (once, reused for all heads) ----
    const int g = tid >> 4;               // bond row 0..63
    const int t = tid & 15;               // 16-thr group lane
    int eg = e0 + g; eg = eg < E_BONDS ? eg : E_BONDS - 1;
    u32 nei[KNB][10];
#pragma unroll
    for (int k = 0; k < KNB; ++k) {
        int nb = bgraph[eg * KNB + k];
        const u32* p = (const u32*)msgIn + (size_t)nb * (HP / 2) + t * 10;
#pragma unroll
        for (int j = 0; j < 10; ++j) nei[k][j] = p[j];
    }

    // ---- stage sMsg: 2560 16B-chunks (40 per row), wave-uniform dests ----
#pragma unroll
    for (int wc = wv; wc < 40; wc += 16) {
        int q   = wc * 64 + lane;
        int row = q / 40, c = q - row * 40;
        int gr  = e0 + row; gr = gr < E_BONDS ? gr : E_BONDS - 1;
        gl2lds16(msgIn + (size_t)gr * HP + ((c ^ (row & 7)) << 3),
                 (char*)sMsg + wc * 1024);
    }
    __syncthreads();   // drains sMsg stage + nei gathers

    f32x4 acc2[5];
#pragma unroll
    for (int nf = 0; nf < 5; ++nf) acc2[nf] = (f32x4){0.f, 0.f, 0.f, 0.f};

    for (int n = 0; n < NH; ++n) {
        // ================= GEMM1: mt_n = sMsg @ WmaT_n =================
        const f16* B1 = WmaT + (size_t)n * HP * HP;
        f32x4 acc1[5];
#pragma unroll
        for (int nf = 0; nf < 5; ++nf) acc1[nf] = (f32x4){0.f, 0.f, 0.f, 0.f};

        for (int kc = 0; kc < 5; ++kc) {
            __syncthreads();               // sB free to overwrite
#pragma unroll
            for (int wc = wv; wc < 40; wc += 16) {
                int q = wc * 64 + lane;
                int brow = q >> 3, c = q & 7;
                gl2lds16(B1 + (size_t)brow * HP + kc * 64 + ((c ^ (brow & 7)) << 3),
                         (char*)sB + wc * 1024);
            }
            __syncthreads();
#pragma unroll
            for (int lk = 0; lk < 2; ++lk) {
                int arow = wm * 16 + rl;
                int ach  = (kc * 8 + lk * 4 + cl) ^ (rl & 7);
                f16x8 a  = *(const f16x8*)&sMsg[arow * HP + ach * 8];
#pragma unroll
                for (int nf = 0; nf < 5; ++nf) {
                    int brow = (wn + nf * 4) * 16 + rl;
                    int bch  = (lk * 4 + cl) ^ (rl & 7);
                    f16x8 b  = *(const f16x8*)&sB[brow * 64 + bch * 8];
                    acc1[nf] = __builtin_amdgcn_mfma_f32_16x16x32_f16(a, b, acc1[nf], 0, 0, 0);
                }
            }
        }
        // scatter mt to sMC (C-layout: row=cl*4+r, col=16*frag+rl)
#pragma unroll
        for (int nf = 0; nf < 5; ++nf) {
#pragma unroll
            for (int r = 0; r < 4; ++r) {
                int row = wm * 16 + cl * 4 + r;
                int col = (wn + nf * 4) * 16 + rl;
                sMC[row * SMC_LD + col] = (f16)acc1[nf][r];
            }
        }
        __syncthreads();

        // ============ scores + softmax + comp (in-place sMC) ============
        {
            const u32* mp = (const u32*)&sMC[g * SMC_LD + t * 20];
            u32 mtv[10];
#pragma unroll
            for (int j = 0; j < 10; ++j) mtv[j] = mp[j];

            float pk[KNB] = {0.f, 0.f, 0.f, 0.f, 0.f, 0.f};
#pragma unroll
            for (int j = 0; j < 10; ++j) {
                float m0 = hlo(mtv[j]), m1 = hhi(mtv[j]);
#pragma unroll
                for (int k = 0; k < KNB; ++k)
                    pk[k] += hlo(nei[k][j]) * m0 + hhi(nei[k][j]) * m1;
            }
#pragma unroll
            for (int s = 1; s < 16; s <<= 1)
#pragma unroll
                for (int k = 0; k < KNB; ++k) pk[k] += __shfl_xor(pk[k], s);

            float mx = pk[0];
#pragma unroll
            for (int k = 1; k < KNB; ++k) mx = fmaxf(mx, pk[k]);
            float w[KNB], sum = 0.f;
#pragma unroll
            for (int k = 0; k < KNB; ++k) { w[k] = __expf(pk[k] - mx); sum += w[k]; }
            float inv = 1.f / sum;
#pragma unroll
            for (int k = 0; k < KNB; ++k) w[k] *= inv;

            u32* cp = (u32*)&sMC[g * SMC_LD + t * 20];
#pragma unroll
            for (int j = 0; j < 10; ++j) {
                float c0 = 0.f, c1 = 0.f;
#pragma unroll
                for (int k = 0; k < KNB; ++k) {
                    c0 += w[k] * hlo(nei[k][j]);
                    c1 += w[k] * hhi(nei[k][j]);
                }
                cp[j] = packh2(c0, c1);
            }
        }
        __syncthreads();

        // ============ GEMM2: acc2 += comp_n @ WhT2_n ============
        const f16* B2 = WhT2 + (size_t)n * HP * HP;
        for (int kc = 0; kc < 5; ++kc) {
            __syncthreads();
#pragma unroll
            for (int wc = wv; wc < 40; wc += 16) {
                int q = wc * 64 + lane;
                int brow = q >> 3, c = q & 7;
                gl2lds16(B2 + (size_t)brow * HP + kc * 64 + ((c ^ (brow & 7)) << 3),
                         (char*)sB + wc * 1024);
            }
            __syncthreads();
#pragma unroll
            for (int lk = 0; lk < 2; ++lk) {
                int arow = wm * 16 + rl;
                f16x8 a  = *(const f16x8*)&sMC[arow * SMC_LD + kc * 64 + lk * 32 + cl * 8];
#pragma unroll
                for (int nf = 0; nf < 5; ++nf) {
                    int brow = (wn + nf * 4) * 16 + rl;
                    int bch  = (lk * 4 + cl) ^ (rl & 7);
                    f16x8 b  = *(const f16x8*)&sB[brow * 64 + bch * 8];
                    acc2[nf] = __builtin_amdgcn_mfma_f32_16x16x32_f16(a, b, acc2[nf], 0, 0, 0);
                }
            }
        }
        __syncthreads();   // protect sMC before next head's scatter
    }

    // ---- epilogue: msg_out = relu(binput + acc2) ----
#pragma unroll
    for (int nf = 0; nf < 5; ++nf) {
#pragma unroll
        for (int r = 0; r < 4; ++r) {
            int gm = e0 + wm * 16 + cl * 4 + r;
            if (gm >= E_BONDS) continue;
            int col = (wn + nf * 4) * 16 + rl;
            size_t ci = (size_t)gm * HP + col;
            float v = acc2[nf][r] + (float)binh[ci];
            msgOut[ci] = (f16)fmaxf(v, 0.f);
        }
    }
}

// ---------------------------------------------------------------------------
// a_nei[a] = sum_k msg[agraph[a][k]]
// ---------------------------------------------------------------------------
__global__ void gather_sum_h_k(const f16* __restrict__ msg,
                               const int* __restrict__ agraph,
                               f16* __restrict__ out) {
    int idx = blockIdx.x * 256 + threadIdx.x;
    if (idx >= NATOMS * (HP / 2)) return;
    int a = idx / (HP / 2), c = idx - a * (HP / 2);
    const int* g = agraph + (size_t)a * KNB;
    float s0 = 0.f, s1 = 0.f;
#pragma unroll
    for (int k = 0; k < KNB; ++k) {
        u32 u = *(const u32*)(msg + (size_t)g[k] * HP + c * 2);
        s0 += hlo(u); s1 += hhi(u);
    }
    ((u32*)out)[idx] = packh2(s0, s1);
}

// ---------------------------------------------------------------------------
__global__ void conv_pad_k(const float* __restrict__ src, f16* __restrict__ dst,
                           int R, int C, int CP) {
    int idx = blockIdx.x * 256 + threadIdx.x;
    if (idx >= R * CP) return;
    int r = idx / CP, c = idx - r * CP;
    dst[idx] = (f16)(c < C ? src[(size_t)r * C + c] : 0.f);
}

// ---------------------------------------------------------------------------
// Weight prep -> f16, padded, K-contiguous layouts.
// mode 0: WiT[320][192]   <- W_i[300][158]
// mode 1: WmaT[1280][320] <- row n*320+d, col h = W_ma[n][h][d]
// mode 2: WhT2[1280][320] <- row n*320+h, col d = W_h[h][n*300+d]
// mode 3: WoA[320][192]   <- W_o cols 0..143
// mode 4: WoB[320][320]   <- W_o cols 144..443
// else:   [320][320]      <- [300][300]
// ---------------------------------------------------------------------------
__global__ void prep_w_k(const float* __restrict__ src, f16* __restrict__ dst,
                         int mode, int R, int CK) {
    int idx = blockIdx.x * 256 + threadIdx.x;
    if (idx >= R * CK) return;
    int r = idx / CK, c = idx - r * CK;
    float v = 0.f;
    if (mode == 0) {
        if (r < HID && c < BONDIN) v = src[r * BONDIN + c];
    } else if (mode == 1) {
        int n = r / HP, d = r - n * HP;
        if (d < HID && c < HID) v = src[((size_t)n * HID + c) * HID + d];
    } else if (mode == 2) {
        int n = r / HP, h = r - n * HP;
        if (h < HID && c < HID) v = src[(size_t)h * (NH * HID) + n * HID + c];
    } else if (mode == 3) {
        if (r < HID && c < AFD) v = src[r * (AFD + HID) + c];
    } else if (mode == 4) {
        if (r < HID && c < HID) v = src[r * (AFD + HID) + AFD + c];
    } else {
        if (r < HID && c < HID) v = src[r * HID + c];
    }
    dst[idx] = (f16)v;
}

// ---------------------------------------------------------------------------
// MFMA molecule attention (unchanged from round 4).
// ---------------------------------------------------------------------------
__global__ __launch_bounds__(256) void mol_attn_mfma_k(
    const f16* __restrict__ atomHh,
    const f16* __restrict__ ah2h,
    f16* __restrict__ comp2h)
{
    __shared__ f16 sCur[64 * 320];
    __shared__ float sP[64][66];
    const int tid  = threadIdx.x;
    const int lane = tid & 63;
    const int wv   = tid >> 6;
    const int m    = blockIdx.x;
    const int rl   = lane & 15, cl = lane >> 4;

#pragma unroll
    for (int i = 0; i < 10; ++i) {
        int g   = i * 256 + wv * 64 + lane;
        int row = g / 40, c = g - row * 40;
        int grow = m * APM + row; grow = grow < NATOMS ? grow : NATOMS - 1;
        const f16* src = atomHh + (size_t)grow * HP + ((c ^ (row & 7)) << 3);
        gl2lds16(src, (char*)sCur + (size_t)(i * 256 + wv * 64) * 16);
    }
    __syncthreads();

    f32x4 acc[4];
#pragma unroll
    for (int nf = 0; nf < 4; ++nf) acc[nf] = (f32x4){0.f, 0.f, 0.f, 0.f};
    int qrow = m * APM + wv * 16 + rl;
    qrow = qrow < NATOMS ? qrow : NATOMS - 1;
    const f16* qbase = ah2h + (size_t)qrow * HP;
#pragma unroll
    for (int kh = 0; kh < 10; ++kh) {
        f16x8 aq = *(const f16x8*)(qbase + kh * 32 + cl * 8);
#pragma unroll
        for (int nf = 0; nf < 4; ++nf) {
            int brow = nf * 16 + rl;
            int ch   = (kh * 4 + cl) ^ (brow & 7);
            f16x8 bv = *(const f16x8*)&sCur[brow * 320 + ch * 8];
            acc[nf] = __builtin_amdgcn_mfma_f32_16x16x32_f16(aq, bv, acc[nf], 0, 0, 0);
        }
    }

#pragma unroll
    for (int r = 0; r < 4; ++r) {
        float s[4];
#pragma unroll
        for (int nf = 0; nf < 4; ++nf) {
            s[nf] = acc[nf][r];
            if (nf == 3 && rl >= 2) s[nf] = -1e30f;
        }
        float mx = fmaxf(fmaxf(s[0], s[1]), fmaxf(s[2], s[3]));
#pragma unroll
        for (int msk = 1; msk < 16; msk <<= 1) mx = fmaxf(mx, __shfl_xor(mx, msk));
        float e[4], sum = 0.f;
#pragma unroll
        for (int nf = 0; nf < 4; ++nf) { e[nf] = __expf(s[nf] - mx); sum += e[nf]; }
#pragma unroll
        for (int msk = 1; msk < 16; msk <<= 1) sum += __shfl_xor(sum, msk);
        float inv = 1.f / sum;
        int a = wv * 16 + cl * 4 + r;
#pragma unroll
        for (int nf = 0; nf < 4; ++nf) sP[a][nf * 16 + rl] = e[nf] * inv;
    }
    __syncthreads();

    const int a  = tid >> 2, hq = tid & 3;
    const bool aval = a < APM;
    const size_t orow = (size_t)(m * APM + a) * HP;
#pragma unroll
    for (int p = 0; p < 2; ++p) {
        float av[40];
#pragma unroll
        for (int i = 0; i < 40; ++i) av[i] = 0.f;
        const int ch0 = p * 20 + hq * 5;
        for (int b = 0; b < APM; ++b) {
            float w = sP[a][b];
#pragma unroll
            for (int i = 0; i < 5; ++i) {
                int ch = (ch0 + i) ^ (b & 7);
                f16x8 cv = *(const f16x8*)&sCur[b * 320 + ch * 8];
#pragma unroll
                for (int j = 0; j < 8; ++j) av[i * 8 + j] += w * (float)cv[j];
            }
        }
        if (aval) {
#pragma unroll
            for (int i = 0; i < 5; ++i) {
                f16x8 o;
#pragma unroll
                for (int j = 0; j < 8; ++j) o[j] = (f16)av[i * 8 + j];
                *(f16x8*)&comp2h[orow + p * 160 + hq * 40 + i * 8] = o;
            }
        }
    }
}

__global__ void mol_reduce_k(const float* __restrict__ atomH,
                             const float* __restrict__ atth,
                             float* __restrict__ out) {
    const int m = blockIdx.x;
    for (int h = threadIdx.x; h < HID; h += 256) {
        float s = 0.f;
        for (int a = 0; a < APM; ++a) {
            size_t i = (size_t)(m * APM + a) * HP + h;
            s += atomH[i] + atth[i];
        }
        out[(size_t)m * HID + h] = s * (1.f / APM);
    }
}

// ---------------------------------------------------------------------------
extern "C" void kernel_launch(void* const* d_in, const int* in_sizes, int n_in,
                              void* d_out, int out_size, void* d_ws, size_t ws_size,
                              hipStream_t stream) {
    const float* fatoms = (const float*)d_in[0];
    const float* fbonds = (const float*)d_in[1];
    const int*   agraph = (const int*)d_in[2];
    const int*   bgraph = (const int*)d_in[3];
    const float* W_i    = (const float*)d_in[4];
    const float* W_ma   = (const float*)d_in[5];
    const float* W_h    = (const float*)d_in[6];
    const float* W_o    = (const float*)d_in[7];
    const float* b_o    = (const float*)d_in[8];
    const float* W_a    = (const float*)d_in[9];
    const float* W_b    = (const float*)d_in[10];
    const float* b_b    = (const float*)d_in[11];
    float* out = (float*)d_out;

    // ---- workspace layout (max 213.7 MB; 233.68 MB proven OK) ----
    char* ws = (char*)d_ws;
    f16* msgA    = (f16*)(ws);                        // [60000][320]
    f16* msgB    = (f16*)(ws + 38400000);             // [60000][320]
    f16* binh    = (f16*)(ws + 76800000);             // [60000][320]
    f16* fbondsh = (f16*)(ws + 115200000);            // [60000][192] (pre-MP)
    // post-MP aliases:
    f16* aneih   = (f16*)(ws);                        // over msgA (dead)
    f16* fatomsh = (f16*)(ws + 38400000);             // over msgB (dead after gather)
    float* atomH = (float*)(ws + 76800000);           // over binh (dead)
    f16* atomHh  = (f16*)(ws + 115200000);
    f16* ah2h    = (f16*)(ws + 134400000);
    f16* comp2h  = (f16*)(ws + 153600000);
    float* atth  = (float*)(ws + 172800000);          // ends 211.2MB
    char* wb = ws + 211200000;
    f16* WiT  = (f16*)(wb);                           // 122880
    f16* WmaT = (f16*)(wb + 122880);                  // 819200
    f16* WhT2 = (f16*)(wb + 942080);                  // 819200
    f16* WoA  = (f16*)(wb + 1761280);                 // 122880
    f16* WoB  = (f16*)(wb + 1884160);                 // 204800
    f16* Wa   = (f16*)(wb + 2088960);                 // 204800
    f16* Wb   = (f16*)(wb + 2293760);                 // 204800 -> ends 213,698,560

    // ---- weight/input prep ----
    prep_w_k<<<dim3((320 * 192 + 255) / 256), dim3(256), 0, stream>>>(W_i, WiT, 0, 320, 192);
    prep_w_k<<<dim3((1280 * 320 + 255) / 256), dim3(256), 0, stream>>>(W_ma, WmaT, 1, 1280, 320);
    prep_w_k<<<dim3((1280 * 320 + 255) / 256), dim3(256), 0, stream>>>(W_h, WhT2, 2, 1280, 320);
    prep_w_k<<<dim3((320 * 192 + 255) / 256), dim3(256), 0, stream>>>(W_o, WoA, 3, 320, 192);
    prep_w_k<<<dim3((320 * 320 + 255) / 256), dim3(256), 0, stream>>>(W_o, WoB, 4, 320, 320);
    prep_w_k<<<dim3((320 * 320 + 255) / 256), dim3(256), 0, stream>>>(W_a, Wa, 5, 320, 320);
    prep_w_k<<<dim3((320 * 320 + 255) / 256), dim3(256), 0, stream>>>(W_b, Wb, 6, 320, 320);
    conv_pad_k<<<dim3((E_BONDS * 192 + 255) / 256), dim3(256), 0, stream>>>(
        fbonds, fbondsh, E_BONDS, BONDIN, 192);

    // ---- binput/message0 ----
    mfma_gemm_k<128, 2><<<dim3(469, 3), dim3(256), 0, stream>>>(
        fbondsh, 192, WiT, 192, E_BONDS, 320, 192, HP, nullptr, binh, nullptr, nullptr, msgA);

    // ---- 3 fused message-passing iterations (ping-pong msgA <-> msgB) ----
    fused_mp_k<<<dim3(938), dim3(1024), 0, stream>>>(msgA, msgB, binh, bgraph, WmaT, WhT2);
    fused_mp_k<<<dim3(938), dim3(1024), 0, stream>>>(msgB, msgA, binh, bgraph, WmaT, WhT2);
    fused_mp_k<<<dim3(938), dim3(1024), 0, stream>>>(msgA, msgB, binh, bgraph, WmaT, WhT2);

    // ---- atom stage ----
    gather_sum_h_k<<<dim3((NATOMS * 160 + 255) / 256), dim3(256), 0, stream>>>(msgB, agraph, aneih);
    conv_pad_k<<<dim3((NATOMS * 192 + 255) / 256), dim3(256), 0, stream>>>(
        fatoms, fatomsh, NATOMS, AFD, 192);
    mfma_gemm_k<128, 0><<<dim3(235, 3), dim3(256), 0, stream>>>(
        fatomsh, 192, WoA, 192, NATOMS, 320, 192, HP, atomH, nullptr, nullptr, nullptr, nullptr);
    mfma_gemm_k<128, 4><<<dim3(235, 3), dim3(256), 0, stream>>>(
        aneih, HP, WoB, HP, NATOMS, 320, HP, HP, atomH, atomHh, b_o, nullptr, nullptr);

    // ---- molecule attention ----
    mfma_gemm_k<128, 1><<<dim3(235, 3), dim3(256), 0, stream>>>(
        atomHh, HP, Wa, HP, NATOMS, 320, HP, HP, nullptr, ah2h, nullptr, nullptr, nullptr);
    mol_attn_mfma_k<<<dim3(NMOLS), dim3(256), 0, stream>>>(atomHh, ah2h, comp2h);
    mfma_gemm_k<128, 5><<<dim3(235, 3), dim3(256), 0, stream>>>(
        comp2h, HP, Wb, HP, NATOMS, 320, HP, HP, atth, nullptr, b_b, nullptr, nullptr);
    mol_reduce_k<<<dim3(NMOLS), dim3(256), 0, stream>>>(atomH, atth, out);
}

// Round 6
// 2796.147 us; speedup vs baseline: 1.1063x; 1.1063x over previous
//
#include <hip/hip_runtime.h>
#include <hip/hip_bf16.h>
#include <math.h>

// Problem constants
#define HID       300
#define HP        320
#define NH        4
#define E_BONDS   60000
#define NATOMS    30000
#define KNB       6
#define NMOLS     600
#define APM       50
#define AFD       144
#define BONDIN    158

typedef unsigned short u16;
typedef unsigned int   u32;
typedef _Float16 f16;
typedef f16   f16x8 __attribute__((ext_vector_type(8)));
typedef float f32x4 __attribute__((ext_vector_type(4)));

// ---------------- helpers ----------------
__device__ inline float hlo(u32 u) { union { u32 i; f16 h[2]; } c; c.i = u; return (float)c.h[0]; }
__device__ inline float hhi(u32 u) { union { u32 i; f16 h[2]; } c; c.i = u; return (float)c.h[1]; }
__device__ inline u32 packh2(float a, float b) {
    union { u32 i; f16 h[2]; } c; c.h[0] = (f16)a; c.h[1] = (f16)b; return c.i;
}

__device__ inline void gl2lds16(const void* g, void* l) {
    __builtin_amdgcn_global_load_lds(
        (const __attribute__((address_space(1))) void*)g,
        (__attribute__((address_space(3))) void*)l, 16, 0, 0);
}

// ---------------------------------------------------------------------------
// MFMA GEMM (proven round 4): C = A[M][lda] @ B[Nb][ldb]^T, f16 in.
// EPI: 0 Cf=v | 1 Ch=h(v) | 2 Ch=h(v),out2=h(relu v) | 3 v+=resid,relu,Ch
//      4 v+=Cf+bias,relu,Cf&Ch | 5 v+=bias,relu,Cf
// ---------------------------------------------------------------------------
template <int BN, int EPI>
__global__ __launch_bounds__(256) void mfma_gemm_k(
    const f16* __restrict__ A, int lda,
    const f16* __restrict__ B, int ldb,
    int M, int Nb, int K, int ldc,
    float* __restrict__ Cf, f16* __restrict__ Ch,
    const float* __restrict__ bias,
    const f16* __restrict__ resid,
    f16* __restrict__ out2)
{
    constexpr int NF = BN / 32;
    __shared__ f16 sA[128 * 64];
    __shared__ f16 sB[BN * 64];
    const int tid  = threadIdx.x;
    const int lane = tid & 63;
    const int wv   = tid >> 6;
    const int wm   = wv >> 1, wn = wv & 1;
    const int m0   = blockIdx.x * 128, n0 = blockIdx.y * BN;

    f32x4 acc[4][NF];
#pragma unroll
    for (int i = 0; i < 4; ++i)
#pragma unroll
        for (int j = 0; j < NF; ++j) acc[i][j] = (f32x4){0.f, 0.f, 0.f, 0.f};

    for (int k0 = 0; k0 < K; k0 += 64) {
        __syncthreads();
#pragma unroll
        for (int i = 0; i < 4; ++i) {
            int o   = (((i * 4 + wv) * 64) + lane) * 16;
            int row = o >> 7;
            int p   = (o >> 4) & 7;
            int gr  = m0 + row; gr = gr < M ? gr : M - 1;
            const f16* g = A + (size_t)gr * lda + k0 + ((p ^ (row & 7)) << 3);
            gl2lds16(g, (char*)sA + (i * 4 + wv) * 1024);
        }
#pragma unroll
        for (int i = 0; i < BN / 32; ++i) {
            int o   = (((i * 4 + wv) * 64) + lane) * 16;
            int row = o >> 7;
            int p   = (o >> 4) & 7;
            int gr  = n0 + row; gr = gr < Nb ? gr : Nb - 1;
            const f16* g = B + (size_t)gr * ldb + k0 + ((p ^ (row & 7)) << 3);
            gl2lds16(g, (char*)sB + (i * 4 + wv) * 1024);
        }
        __syncthreads();

        const int rl = lane & 15, cl = lane >> 4;
#pragma unroll
        for (int kh = 0; kh < 2; ++kh) {
            f16x8 af[4], bfr[NF];
#pragma unroll
            for (int mf = 0; mf < 4; ++mf) {
                int row = wm * 64 + mf * 16 + rl;
                int ch  = (kh * 4 + cl) ^ (row & 7);
                af[mf]  = *(const f16x8*)&sA[row * 64 + ch * 8];
            }
#pragma unroll
            for (int nf = 0; nf < NF; ++nf) {
                int row = wn * (BN / 2) + nf * 16 + rl;
                int ch  = (kh * 4 + cl) ^ (row & 7);
                bfr[nf] = *(const f16x8*)&sB[row * 64 + ch * 8];
            }
#pragma unroll
            for (int mf = 0; mf < 4; ++mf)
#pragma unroll
                for (int nf = 0; nf < NF; ++nf)
                    acc[mf][nf] = __builtin_amdgcn_mfma_f32_16x16x32_f16(
                        af[mf], bfr[nf], acc[mf][nf], 0, 0, 0);
        }
    }

    const int rl = lane & 15, cl = lane >> 4;
#pragma unroll
    for (int mf = 0; mf < 4; ++mf) {
#pragma unroll
        for (int r = 0; r < 4; ++r) {
            int gm = m0 + wm * 64 + mf * 16 + cl * 4 + r;
            if (gm >= M) continue;
#pragma unroll
            for (int nf = 0; nf < NF; ++nf) {
                int gn = n0 + wn * (BN / 2) + nf * 16 + rl;
                if (gn >= ldc) continue;
                float v = acc[mf][nf][r];
                size_t ci = (size_t)gm * ldc + gn;
                if (EPI == 0) {
                    Cf[ci] = v;
                } else if (EPI == 1) {
                    Ch[ci] = (f16)v;
                } else if (EPI == 2) {
                    Ch[ci] = (f16)v;
                    out2[ci] = (f16)fmaxf(v, 0.f);
                } else if (EPI == 3) {
                    v += (float)resid[ci];
                    Ch[ci] = (f16)fmaxf(v, 0.f);
                } else if (EPI == 4) {
                    v += Cf[ci];
                    v += (gn < HID) ? bias[gn] : 0.f;
                    v = fmaxf(v, 0.f);
                    Cf[ci] = v; Ch[ci] = (f16)v;
                } else {
                    v += (gn < HID) ? bias[gn] : 0.f;
                    Cf[ci] = fmaxf(v, 0.f);
                }
            }
        }
    }
}

// ---------------------------------------------------------------------------
// FUSED message-passing iteration (v2 — spill-free).
// Per head: GEMM1 (mt = sMsg @ WmaT_n) -> sMC; re-gather nei rows (transient
// 60 VGPR, scoped to this head); scores/softmax/comp in-place in sMC;
// GEMM2 partial (acc2 += comp @ WhT2_n).  Epilogue relu(binput + acc2).
// Block = 64 bonds, 1024 thr = 16 waves (4m x 4n). VGPR budget 128 via
// __launch_bounds__(1024,4); nei live-range confined to score section.
// ---------------------------------------------------------------------------
#define SMC_LD 328   // 320 + 8 pad

__global__ __launch_bounds__(1024, 4) void fused_mp_k(
    const f16* __restrict__ msgIn,   // [E][320]
    f16* __restrict__ msgOut,        // [E][320]
    const f16* __restrict__ binh,    // [E][320]
    const int* __restrict__ bgraph,  // [E][6]
    const f16* __restrict__ WmaT,    // [4*320][320]  row n*320+d, col h
    const f16* __restrict__ WhT2)    // [4*320][320]  row n*320+h, col d
{
    __shared__ f16 sMsg[64 * 320];        // 40 KB, XOR-swizzled 16B chunks
    __shared__ f16 sMC[64 * SMC_LD];      // 41 KB, mt/comp (padded rows)
    __shared__ f16 sB[320 * 64];          // 40 KB, weight k-chunk (swizzled)

    const int tid  = threadIdx.x;
    const int lane = tid & 63;
    const int wv   = tid >> 6;            // 0..15
    const int wm   = wv >> 2;             // 0..3
    const int wn   = wv & 3;              // 0..3
    const int rl   = lane & 15, cl = lane >> 4;
    const int e0   = blockIdx.x * 64;

    const int g = tid >> 4;               // bond row 0..63
    const int t = tid & 15;               // 16-thr group lane
    int eg = e0 + g; eg = eg < E_BONDS ? eg : E_BONDS - 1;
    int nbidx[KNB];
#pragma unroll
    for (int k = 0; k < KNB; ++k) nbidx[k] = bgraph[eg * KNB + k];

    // ---- stage sMsg: 2560 16B-chunks (40 per row), wave-uniform dests ----
    for (int wc = wv; wc < 40; wc += 16) {
        int q   = wc * 64 + lane;
        int row = q / 40, c = q - row * 40;
        int gr  = e0 + row; gr = gr < E_BONDS ? gr : E_BONDS - 1;
        gl2lds16(msgIn + (size_t)gr * HP + ((c ^ (row & 7)) << 3),
                 (char*)sMsg + wc * 1024);
    }
    __syncthreads();

    f32x4 acc2[5];
#pragma unroll
    for (int nf = 0; nf < 5; ++nf) acc2[nf] = (f32x4){0.f, 0.f, 0.f, 0.f};

#pragma unroll 1
    for (int n = 0; n < NH; ++n) {
        // ================= GEMM1: mt_n = sMsg @ WmaT_n =================
        const f16* B1 = WmaT + (size_t)n * HP * HP;
        f32x4 acc1[5];
#pragma unroll
        for (int nf = 0; nf < 5; ++nf) acc1[nf] = (f32x4){0.f, 0.f, 0.f, 0.f};

        for (int kc = 0; kc < 5; ++kc) {
            __syncthreads();
            for (int wc = wv; wc < 40; wc += 16) {
                int q = wc * 64 + lane;
                int brow = q >> 3, c = q & 7;
                gl2lds16(B1 + (size_t)brow * HP + kc * 64 + ((c ^ (brow & 7)) << 3),
                         (char*)sB + wc * 1024);
            }
            __syncthreads();
#pragma unroll
            for (int lk = 0; lk < 2; ++lk) {
                int arow = wm * 16 + rl;
                int ach  = (kc * 8 + lk * 4 + cl) ^ (rl & 7);
                f16x8 a  = *(const f16x8*)&sMsg[arow * HP + ach * 8];
#pragma unroll
                for (int nf = 0; nf < 5; ++nf) {
                    int brow = (wn + nf * 4) * 16 + rl;
                    int bch  = (lk * 4 + cl) ^ (rl & 7);
                    f16x8 b  = *(const f16x8*)&sB[brow * 64 + bch * 8];
                    acc1[nf] = __builtin_amdgcn_mfma_f32_16x16x32_f16(a, b, acc1[nf], 0, 0, 0);
                }
            }
        }
        // scatter mt to sMC
#pragma unroll
        for (int nf = 0; nf < 5; ++nf) {
#pragma unroll
            for (int r = 0; r < 4; ++r) {
                int row = wm * 16 + cl * 4 + r;
                int col = (wn + nf * 4) * 16 + rl;
                sMC[row * SMC_LD + col] = (f16)acc1[nf][r];
            }
        }
        __syncthreads();

        // ===== re-gather nei (transient; opaque offset blocks LICM/CSE) =====
        {
            int zero = 0;
            asm volatile("" : "+v"(zero));
            const u32* mb = (const u32*)msgIn + zero + t * 10;
            u32 nei[KNB][10];
#pragma unroll
            for (int k = 0; k < KNB; ++k) {
                const u32* p = mb + (size_t)nbidx[k] * (HP / 2);
#pragma unroll
                for (int j = 0; j < 10; ++j) nei[k][j] = p[j];
            }

            // ---- scores ----
            float pk[KNB] = {0.f, 0.f, 0.f, 0.f, 0.f, 0.f};
            const u32* mp = (const u32*)&sMC[g * SMC_LD] + t * 10;
#pragma unroll
            for (int j = 0; j < 10; ++j) {
                u32 mtv = mp[j];
                float m0 = hlo(mtv), m1 = hhi(mtv);
#pragma unroll
                for (int k = 0; k < KNB; ++k)
                    pk[k] += hlo(nei[k][j]) * m0 + hhi(nei[k][j]) * m1;
            }
#pragma unroll
            for (int s = 1; s < 16; s <<= 1)
#pragma unroll
                for (int k = 0; k < KNB; ++k) pk[k] += __shfl_xor(pk[k], s);

            float mx = pk[0];
#pragma unroll
            for (int k = 1; k < KNB; ++k) mx = fmaxf(mx, pk[k]);
            float w[KNB], sum = 0.f;
#pragma unroll
            for (int k = 0; k < KNB; ++k) { w[k] = __expf(pk[k] - mx); sum += w[k]; }
            float inv = 1.f / sum;
#pragma unroll
            for (int k = 0; k < KNB; ++k) w[k] *= inv;

            // ---- comp (in-place over mt) ----
            u32* cp = (u32*)&sMC[g * SMC_LD] + t * 10;
#pragma unroll
            for (int j = 0; j < 10; ++j) {
                float c0 = 0.f, c1 = 0.f;
#pragma unroll
                for (int k = 0; k < KNB; ++k) {
                    c0 += w[k] * hlo(nei[k][j]);
                    c1 += w[k] * hhi(nei[k][j]);
                }
                cp[j] = packh2(c0, c1);
            }
        }
        __syncthreads();

        // ============ GEMM2: acc2 += comp_n @ WhT2_n ============
        const f16* B2 = WhT2 + (size_t)n * HP * HP;
        for (int kc = 0; kc < 5; ++kc) {
            __syncthreads();
            for (int wc = wv; wc < 40; wc += 16) {
                int q = wc * 64 + lane;
                int brow = q >> 3, c = q & 7;
                gl2lds16(B2 + (size_t)brow * HP + kc * 64 + ((c ^ (brow & 7)) << 3),
                         (char*)sB + wc * 1024);
            }
            __syncthreads();
#pragma unroll
            for (int lk = 0; lk < 2; ++lk) {
                int arow = wm * 16 + rl;
                f16x8 a  = *(const f16x8*)&sMC[arow * SMC_LD + kc * 64 + lk * 32 + cl * 8];
#pragma unroll
                for (int nf = 0; nf < 5; ++nf) {
                    int brow = (wn + nf * 4) * 16 + rl;
                    int bch  = (lk * 4 + cl) ^ (rl & 7);
                    f16x8 b  = *(const f16x8*)&sB[brow * 64 + bch * 8];
                    acc2[nf] = __builtin_amdgcn_mfma_f32_16x16x32_f16(a, b, acc2[nf], 0, 0, 0);
                }
            }
        }
        __syncthreads();   // protect sMC before next head's scatter
    }

    // ---- epilogue: msg_out = relu(binput + acc2) ----
#pragma unroll
    for (int nf = 0; nf < 5; ++nf) {
#pragma unroll
        for (int r = 0; r < 4; ++r) {
            int gm = e0 + wm * 16 + cl * 4 + r;
            if (gm >= E_BONDS) continue;
            int col = (wn + nf * 4) * 16 + rl;
            size_t ci = (size_t)gm * HP + col;
            float v = acc2[nf][r] + (float)binh[ci];
            msgOut[ci] = (f16)fmaxf(v, 0.f);
        }
    }
}

// ---------------------------------------------------------------------------
// a_nei[a] = sum_k msg[agraph[a][k]]
// ---------------------------------------------------------------------------
__global__ void gather_sum_h_k(const f16* __restrict__ msg,
                               const int* __restrict__ agraph,
                               f16* __restrict__ out) {
    int idx = blockIdx.x * 256 + threadIdx.x;
    if (idx >= NATOMS * (HP / 2)) return;
    int a = idx / (HP / 2), c = idx - a * (HP / 2);
    const int* g = agraph + (size_t)a * KNB;
    float s0 = 0.f, s1 = 0.f;
#pragma unroll
    for (int k = 0; k < KNB; ++k) {
        u32 u = *(const u32*)(msg + (size_t)g[k] * HP + c * 2);
        s0 += hlo(u); s1 += hhi(u);
    }
    ((u32*)out)[idx] = packh2(s0, s1);
}

// ---------------------------------------------------------------------------
__global__ void conv_pad_k(const float* __restrict__ src, f16* __restrict__ dst,
                           int R, int C, int CP) {
    int idx = blockIdx.x * 256 + threadIdx.x;
    if (idx >= R * CP) return;
    int r = idx / CP, c = idx - r * CP;
    dst[idx] = (f16)(c < C ? src[(size_t)r * C + c] : 0.f);
}

// ---------------------------------------------------------------------------
// Weight prep -> f16, padded, K-contiguous layouts.
// mode 0: WiT[320][192]   <- W_i[300][158]
// mode 1: WmaT[1280][320] <- row n*320+d, col h = W_ma[n][h][d]
// mode 2: WhT2[1280][320] <- row n*320+h, col d = W_h[h][n*300+d]
// mode 3: WoA[320][192]   <- W_o cols 0..143
// mode 4: WoB[320][320]   <- W_o cols 144..443
// else:   [320][320]      <- [300][300]
// ---------------------------------------------------------------------------
__global__ void prep_w_k(const float* __restrict__ src, f16* __restrict__ dst,
                         int mode, int R, int CK) {
    int idx = blockIdx.x * 256 + threadIdx.x;
    if (idx >= R * CK) return;
    int r = idx / CK, c = idx - r * CK;
    float v = 0.f;
    if (mode == 0) {
        if (r < HID && c < BONDIN) v = src[r * BONDIN + c];
    } else if (mode == 1) {
        int n = r / HP, d = r - n * HP;
        if (d < HID && c < HID) v = src[((size_t)n * HID + c) * HID + d];
    } else if (mode == 2) {
        int n = r / HP, h = r - n * HP;
        if (h < HID && c < HID) v = src[(size_t)h * (NH * HID) + n * HID + c];
    } else if (mode == 3) {
        if (r < HID && c < AFD) v = src[r * (AFD + HID) + c];
    } else if (mode == 4) {
        if (r < HID && c < HID) v = src[r * (AFD + HID) + AFD + c];
    } else {
        if (r < HID && c < HID) v = src[r * HID + c];
    }
    dst[idx] = (f16)v;
}

// ---------------------------------------------------------------------------
// MFMA molecule attention (unchanged from round 4).
// ---------------------------------------------------------------------------
__global__ __launch_bounds__(256) void mol_attn_mfma_k(
    const f16* __restrict__ atomHh,
    const f16* __restrict__ ah2h,
    f16* __restrict__ comp2h)
{
    __shared__ f16 sCur[64 * 320];
    __shared__ float sP[64][66];
    const int tid  = threadIdx.x;
    const int lane = tid & 63;
    const int wv   = tid >> 6;
    const int m    = blockIdx.x;
    const int rl   = lane & 15, cl = lane >> 4;

#pragma unroll
    for (int i = 0; i < 10; ++i) {
        int g   = i * 256 + wv * 64 + lane;
        int row = g / 40, c = g - row * 40;
        int grow = m * APM + row; grow = grow < NATOMS ? grow : NATOMS - 1;
        const f16* src = atomHh + (size_t)grow * HP + ((c ^ (row & 7)) << 3);
        gl2lds16(src, (char*)sCur + (size_t)(i * 256 + wv * 64) * 16);
    }
    __syncthreads();

    f32x4 acc[4];
#pragma unroll
    for (int nf = 0; nf < 4; ++nf) acc[nf] = (f32x4){0.f, 0.f, 0.f, 0.f};
    int qrow = m * APM + wv * 16 + rl;
    qrow = qrow < NATOMS ? qrow : NATOMS - 1;
    const f16* qbase = ah2h + (size_t)qrow * HP;
#pragma unroll
    for (int kh = 0; kh < 10; ++kh) {
        f16x8 aq = *(const f16x8*)(qbase + kh * 32 + cl * 8);
#pragma unroll
        for (int nf = 0; nf < 4; ++nf) {
            int brow = nf * 16 + rl;
            int ch   = (kh * 4 + cl) ^ (brow & 7);
            f16x8 bv = *(const f16x8*)&sCur[brow * 320 + ch * 8];
            acc[nf] = __builtin_amdgcn_mfma_f32_16x16x32_f16(aq, bv, acc[nf], 0, 0, 0);
        }
    }

#pragma unroll
    for (int r = 0; r < 4; ++r) {
        float s[4];
#pragma unroll
        for (int nf = 0; nf < 4; ++nf) {
            s[nf] = acc[nf][r];
            if (nf == 3 && rl >= 2) s[nf] = -1e30f;
        }
        float mx = fmaxf(fmaxf(s[0], s[1]), fmaxf(s[2], s[3]));
#pragma unroll
        for (int msk = 1; msk < 16; msk <<= 1) mx = fmaxf(mx, __shfl_xor(mx, msk));
        float e[4], sum = 0.f;
#pragma unroll
        for (int nf = 0; nf < 4; ++nf) { e[nf] = __expf(s[nf] - mx); sum += e[nf]; }
#pragma unroll
        for (int msk = 1; msk < 16; msk <<= 1) sum += __shfl_xor(sum, msk);
        float inv = 1.f / sum;
        int a = wv * 16 + cl * 4 + r;
#pragma unroll
        for (int nf = 0; nf < 4; ++nf) sP[a][nf * 16 + rl] = e[nf] * inv;
    }
    __syncthreads();

    const int a  = tid >> 2, hq = tid & 3;
    const bool aval = a < APM;
    const size_t orow = (size_t)(m * APM + a) * HP;
#pragma unroll
    for (int p = 0; p < 2; ++p) {
        float av[40];
#pragma unroll
        for (int i = 0; i < 40; ++i) av[i] = 0.f;
        const int ch0 = p * 20 + hq * 5;
        for (int b = 0; b < APM; ++b) {
            float w = sP[a][b];
#pragma unroll
            for (int i = 0; i < 5; ++i) {
                int ch = (ch0 + i) ^ (b & 7);
                f16x8 cv = *(const f16x8*)&sCur[b * 320 + ch * 8];
#pragma unroll
                for (int j = 0; j < 8; ++j) av[i * 8 + j] += w * (float)cv[j];
            }
        }
        if (aval) {
#pragma unroll
            for (int i = 0; i < 5; ++i) {
                f16x8 o;
#pragma unroll
                for (int j = 0; j < 8; ++j) o[j] = (f16)av[i * 8 + j];
                *(f16x8*)&comp2h[orow + p * 160 + hq * 40 + i * 8] = o;
            }
        }
    }
}

__global__ void mol_reduce_k(const float* __restrict__ atomH,
                             const float* __restrict__ atth,
                             float* __restrict__ out) {
    const int m = blockIdx.x;
    for (int h = threadIdx.x; h < HID; h += 256) {
        float s = 0.f;
        for (int a = 0; a < APM; ++a) {
            size_t i = (size_t)(m * APM + a) * HP + h;
            s += atomH[i] + atth[i];
        }
        out[(size_t)m * HID + h] = s * (1.f / APM);
    }
}

// ---------------------------------------------------------------------------
extern "C" void kernel_launch(void* const* d_in, const int* in_sizes, int n_in,
                              void* d_out, int out_size, void* d_ws, size_t ws_size,
                              hipStream_t stream) {
    const float* fatoms = (const float*)d_in[0];
    const float* fbonds = (const float*)d_in[1];
    const int*   agraph = (const int*)d_in[2];
    const int*   bgraph = (const int*)d_in[3];
    const float* W_i    = (const float*)d_in[4];
    const float* W_ma   = (const float*)d_in[5];
    const float* W_h    = (const float*)d_in[6];
    const float* W_o    = (const float*)d_in[7];
    const float* b_o    = (const float*)d_in[8];
    const float* W_a    = (const float*)d_in[9];
    const float* W_b    = (const float*)d_in[10];
    const float* b_b    = (const float*)d_in[11];
    float* out = (float*)d_out;

    // ---- workspace layout (max 213.7 MB) ----
    char* ws = (char*)d_ws;
    f16* msgA    = (f16*)(ws);                        // [60000][320]
    f16* msgB    = (f16*)(ws + 38400000);             // [60000][320]
    f16* binh    = (f16*)(ws + 76800000);             // [60000][320]
    f16* fbondsh = (f16*)(ws + 115200000);            // [60000][192] (pre-MP)
    // post-MP aliases:
    f16* aneih   = (f16*)(ws);                        // over msgA (dead)
    f16* fatomsh = (f16*)(ws + 38400000);             // over msgB (dead after gather)
    float* atomH = (float*)(ws + 76800000);           // over binh (dead)
    f16* atomHh  = (f16*)(ws + 115200000);
    f16* ah2h    = (f16*)(ws + 134400000);
    f16* comp2h  = (f16*)(ws + 153600000);
    float* atth  = (float*)(ws + 172800000);          // ends 211.2MB
    char* wb = ws + 211200000;
    f16* WiT  = (f16*)(wb);
    f16* WmaT = (f16*)(wb + 122880);
    f16* WhT2 = (f16*)(wb + 942080);
    f16* WoA  = (f16*)(wb + 1761280);
    f16* WoB  = (f16*)(wb + 1884160);
    f16* Wa   = (f16*)(wb + 2088960);
    f16* Wb   = (f16*)(wb + 2293760);

    // ---- weight/input prep ----
    prep_w_k<<<dim3((320 * 192 + 255) / 256), dim3(256), 0, stream>>>(W_i, WiT, 0, 320, 192);
    prep_w_k<<<dim3((1280 * 320 + 255) / 256), dim3(256), 0, stream>>>(W_ma, WmaT, 1, 1280, 320);
    prep_w_k<<<dim3((1280 * 320 + 255) / 256), dim3(256), 0, stream>>>(W_h, WhT2, 2, 1280, 320);
    prep_w_k<<<dim3((320 * 192 + 255) / 256), dim3(256), 0, stream>>>(W_o, WoA, 3, 320, 192);
    prep_w_k<<<dim3((320 * 320 + 255) / 256), dim3(256), 0, stream>>>(W_o, WoB, 4, 320, 320);
    prep_w_k<<<dim3((320 * 320 + 255) / 256), dim3(256), 0, stream>>>(W_a, Wa, 5, 320, 320);
    prep_w_k<<<dim3((320 * 320 + 255) / 256), dim3(256), 0, stream>>>(W_b, Wb, 6, 320, 320);
    conv_pad_k<<<dim3((E_BONDS * 192 + 255) / 256), dim3(256), 0, stream>>>(
        fbonds, fbondsh, E_BONDS, BONDIN, 192);

    // ---- binput/message0 ----
    mfma_gemm_k<128, 2><<<dim3(469, 3), dim3(256), 0, stream>>>(
        fbondsh, 192, WiT, 192, E_BONDS, 320, 192, HP, nullptr, binh, nullptr, nullptr, msgA);

    // ---- 3 fused message-passing iterations (ping-pong msgA <-> msgB) ----
    fused_mp_k<<<dim3(938), dim3(1024), 0, stream>>>(msgA, msgB, binh, bgraph, WmaT, WhT2);
    fused_mp_k<<<dim3(938), dim3(1024), 0, stream>>>(msgB, msgA, binh, bgraph, WmaT, WhT2);
    fused_mp_k<<<dim3(938), dim3(1024), 0, stream>>>(msgA, msgB, binh, bgraph, WmaT, WhT2);

    // ---- atom stage ----
    gather_sum_h_k<<<dim3((NATOMS * 160 + 255) / 256), dim3(256), 0, stream>>>(msgB, agraph, aneih);
    conv_pad_k<<<dim3((NATOMS * 192 + 255) / 256), dim3(256), 0, stream>>>(
        fatoms, fatomsh, NATOMS, AFD, 192);
    mfma_gemm_k<128, 0><<<dim3(235, 3), dim3(256), 0, stream>>>(
        fatomsh, 192, WoA, 192, NATOMS, 320, 192, HP, atomH, nullptr, nullptr, nullptr, nullptr);
    mfma_gemm_k<128, 4><<<dim3(235, 3), dim3(256), 0, stream>>>(
        aneih, HP, WoB, HP, NATOMS, 320, HP, HP, atomH, atomHh, b_o, nullptr, nullptr);

    // ---- molecule attention ----
    mfma_gemm_k<128, 1><<<dim3(235, 3), dim3(256), 0, stream>>>(
        atomHh, HP, Wa, HP, NATOMS, 320, HP, HP, nullptr, ah2h, nullptr, nullptr, nullptr);
    mol_attn_mfma_k<<<dim3(NMOLS), dim3(256), 0, stream>>>(atomHh, ah2h, comp2h);
    mfma_gemm_k<128, 5><<<dim3(235, 3), dim3(256), 0, stream>>>(
        comp2h, HP, Wb, HP, NATOMS, 320, HP, HP, atth, nullptr, b_b, nullptr, nullptr);
    mol_reduce_k<<<dim3(NMOLS), dim3(256), 0, stream>>>(atomH, atth, out);
}

// Round 7
// 2037.145 us; speedup vs baseline: 1.5185x; 1.3726x over previous
//
#include <hip/hip_runtime.h>
#include <hip/hip_bf16.h>
#include <math.h>

// Problem constants
#define HID       300
#define HP        320
#define NH        4
#define E_BONDS   60000
#define NATOMS    30000
#define KNB       6
#define NMOLS     600
#define APM       50
#define AFD       144
#define BONDIN    158

typedef unsigned short u16;
typedef unsigned int   u32;
typedef _Float16 f16;
typedef f16   f16x8 __attribute__((ext_vector_type(8)));
typedef float f32x4 __attribute__((ext_vector_type(4)));

// ---------------- helpers ----------------
__device__ inline float hlo(u32 u) { union { u32 i; f16 h[2]; } c; c.i = u; return (float)c.h[0]; }
__device__ inline float hhi(u32 u) { union { u32 i; f16 h[2]; } c; c.i = u; return (float)c.h[1]; }
__device__ inline u32 packh2(float a, float b) {
    union { u32 i; f16 h[2]; } c; c.h[0] = (f16)a; c.h[1] = (f16)b; return c.i;
}

__device__ inline void gl2lds16(const void* g, void* l) {
    __builtin_amdgcn_global_load_lds(
        (const __attribute__((address_space(1))) void*)g,
        (__attribute__((address_space(3))) void*)l, 16, 0, 0);
}

// ---------------------------------------------------------------------------
// MFMA GEMM (proven round 4): C = A[M][lda] @ B[Nb][ldb]^T, f16 in.
// EPI: 0 Cf=v | 1 Ch=h(v) | 2 Ch=h(v),out2=h(relu v) | 3 v+=resid,relu,Ch
//      4 v+=Cf+bias,relu,Cf&Ch | 5 v+=bias,relu,Cf
// ---------------------------------------------------------------------------
template <int BN, int EPI>
__global__ __launch_bounds__(256) void mfma_gemm_k(
    const f16* __restrict__ A, int lda,
    const f16* __restrict__ B, int ldb,
    int M, int Nb, int K, int ldc,
    float* __restrict__ Cf, f16* __restrict__ Ch,
    const float* __restrict__ bias,
    const f16* __restrict__ resid,
    f16* __restrict__ out2)
{
    constexpr int NF = BN / 32;
    __shared__ f16 sA[128 * 64];
    __shared__ f16 sB[BN * 64];
    const int tid  = threadIdx.x;
    const int lane = tid & 63;
    const int wv   = tid >> 6;
    const int wm   = wv >> 1, wn = wv & 1;
    const int m0   = blockIdx.x * 128, n0 = blockIdx.y * BN;

    f32x4 acc[4][NF];
#pragma unroll
    for (int i = 0; i < 4; ++i)
#pragma unroll
        for (int j = 0; j < NF; ++j) acc[i][j] = (f32x4){0.f, 0.f, 0.f, 0.f};

    for (int k0 = 0; k0 < K; k0 += 64) {
        __syncthreads();
#pragma unroll
        for (int i = 0; i < 4; ++i) {
            int o   = (((i * 4 + wv) * 64) + lane) * 16;
            int row = o >> 7;
            int p   = (o >> 4) & 7;
            int gr  = m0 + row; gr = gr < M ? gr : M - 1;
            const f16* g = A + (size_t)gr * lda + k0 + ((p ^ (row & 7)) << 3);
            gl2lds16(g, (char*)sA + (i * 4 + wv) * 1024);
        }
#pragma unroll
        for (int i = 0; i < BN / 32; ++i) {
            int o   = (((i * 4 + wv) * 64) + lane) * 16;
            int row = o >> 7;
            int p   = (o >> 4) & 7;
            int gr  = n0 + row; gr = gr < Nb ? gr : Nb - 1;
            const f16* g = B + (size_t)gr * ldb + k0 + ((p ^ (row & 7)) << 3);
            gl2lds16(g, (char*)sB + (i * 4 + wv) * 1024);
        }
        __syncthreads();

        const int rl = lane & 15, cl = lane >> 4;
#pragma unroll
        for (int kh = 0; kh < 2; ++kh) {
            f16x8 af[4], bfr[NF];
#pragma unroll
            for (int mf = 0; mf < 4; ++mf) {
                int row = wm * 64 + mf * 16 + rl;
                int ch  = (kh * 4 + cl) ^ (row & 7);
                af[mf]  = *(const f16x8*)&sA[row * 64 + ch * 8];
            }
#pragma unroll
            for (int nf = 0; nf < NF; ++nf) {
                int row = wn * (BN / 2) + nf * 16 + rl;
                int ch  = (kh * 4 + cl) ^ (row & 7);
                bfr[nf] = *(const f16x8*)&sB[row * 64 + ch * 8];
            }
#pragma unroll
            for (int mf = 0; mf < 4; ++mf)
#pragma unroll
                for (int nf = 0; nf < NF; ++nf)
                    acc[mf][nf] = __builtin_amdgcn_mfma_f32_16x16x32_f16(
                        af[mf], bfr[nf], acc[mf][nf], 0, 0, 0);
        }
    }

    const int rl = lane & 15, cl = lane >> 4;
#pragma unroll
    for (int mf = 0; mf < 4; ++mf) {
#pragma unroll
        for (int r = 0; r < 4; ++r) {
            int gm = m0 + wm * 64 + mf * 16 + cl * 4 + r;
            if (gm >= M) continue;
#pragma unroll
            for (int nf = 0; nf < NF; ++nf) {
                int gn = n0 + wn * (BN / 2) + nf * 16 + rl;
                if (gn >= ldc) continue;
                float v = acc[mf][nf][r];
                size_t ci = (size_t)gm * ldc + gn;
                if (EPI == 0) {
                    Cf[ci] = v;
                } else if (EPI == 1) {
                    Ch[ci] = (f16)v;
                } else if (EPI == 2) {
                    Ch[ci] = (f16)v;
                    out2[ci] = (f16)fmaxf(v, 0.f);
                } else if (EPI == 3) {
                    v += (float)resid[ci];
                    Ch[ci] = (f16)fmaxf(v, 0.f);
                } else if (EPI == 4) {
                    v += Cf[ci];
                    v += (gn < HID) ? bias[gn] : 0.f;
                    v = fmaxf(v, 0.f);
                    Cf[ci] = v; Ch[ci] = (f16)v;
                } else {
                    v += (gn < HID) ? bias[gn] : 0.f;
                    Cf[ci] = fmaxf(v, 0.f);
                }
            }
        }
    }
}

// ---------------------------------------------------------------------------
// FUSED message-passing iteration (v3 — spill-free score phase).
// Per head: GEMM1 (mt = sMsg @ WmaT_n) -> sMC; then score/softmax/comp with
// 32 THREADS PER BOND in TWO passes (bonds 0-31, 32-63): nei[6][5]=30 VGPR
// per thread (fits the 64-VGPR reality of 1024-thr blocks, no spill);
// GEMM2 partial (acc2 += comp @ WhT2_n). Epilogue relu(binput + acc2).
// ---------------------------------------------------------------------------
#define SMC_LD 328   // 320 + 8 pad

__global__ __launch_bounds__(1024, 4) void fused_mp_k(
    const f16* __restrict__ msgIn,   // [E][320]
    f16* __restrict__ msgOut,        // [E][320]
    const f16* __restrict__ binh,    // [E][320]
    const int* __restrict__ bgraph,  // [E][6]
    const f16* __restrict__ WmaT,    // [4*320][320]  row n*320+d, col h
    const f16* __restrict__ WhT2)    // [4*320][320]  row n*320+h, col d
{
    __shared__ f16 sMsg[64 * 320];        // 40 KB, XOR-swizzled 16B chunks
    __shared__ f16 sMC[64 * SMC_LD];      // 41 KB, mt/comp (padded rows)
    __shared__ f16 sB[320 * 64];          // 40 KB, weight k-chunk (swizzled)

    const int tid  = threadIdx.x;
    const int lane = tid & 63;
    const int wv   = tid >> 6;            // 0..15
    const int wm   = wv >> 2;             // 0..3
    const int wn   = wv & 3;              // 0..3
    const int rl   = lane & 15, cl = lane >> 4;
    const int e0   = blockIdx.x * 64;

    // ---- stage sMsg: 2560 16B-chunks (40 per row), wave-uniform dests ----
    for (int wc = wv; wc < 40; wc += 16) {
        int q   = wc * 64 + lane;
        int row = q / 40, c = q - row * 40;
        int gr  = e0 + row; gr = gr < E_BONDS ? gr : E_BONDS - 1;
        gl2lds16(msgIn + (size_t)gr * HP + ((c ^ (row & 7)) << 3),
                 (char*)sMsg + wc * 1024);
    }
    __syncthreads();

    f32x4 acc2[5];
#pragma unroll
    for (int nf = 0; nf < 5; ++nf) acc2[nf] = (f32x4){0.f, 0.f, 0.f, 0.f};

#pragma unroll 1
    for (int n = 0; n < NH; ++n) {
        // ================= GEMM1: mt_n = sMsg @ WmaT_n =================
        const f16* B1 = WmaT + (size_t)n * HP * HP;
        f32x4 acc1[5];
#pragma unroll
        for (int nf = 0; nf < 5; ++nf) acc1[nf] = (f32x4){0.f, 0.f, 0.f, 0.f};

        for (int kc = 0; kc < 5; ++kc) {
            __syncthreads();
            for (int wc = wv; wc < 40; wc += 16) {
                int q = wc * 64 + lane;
                int brow = q >> 3, c = q & 7;
                gl2lds16(B1 + (size_t)brow * HP + kc * 64 + ((c ^ (brow & 7)) << 3),
                         (char*)sB + wc * 1024);
            }
            __syncthreads();
#pragma unroll
            for (int lk = 0; lk < 2; ++lk) {
                int arow = wm * 16 + rl;
                int ach  = (kc * 8 + lk * 4 + cl) ^ (rl & 7);
                f16x8 a  = *(const f16x8*)&sMsg[arow * HP + ach * 8];
#pragma unroll
                for (int nf = 0; nf < 5; ++nf) {
                    int brow = (wn + nf * 4) * 16 + rl;
                    int bch  = (lk * 4 + cl) ^ (rl & 7);
                    f16x8 b  = *(const f16x8*)&sB[brow * 64 + bch * 8];
                    acc1[nf] = __builtin_amdgcn_mfma_f32_16x16x32_f16(a, b, acc1[nf], 0, 0, 0);
                }
            }
        }
        // scatter mt to sMC
#pragma unroll
        for (int nf = 0; nf < 5; ++nf) {
#pragma unroll
            for (int r = 0; r < 4; ++r) {
                int row = wm * 16 + cl * 4 + r;
                int col = (wn + nf * 4) * 16 + rl;
                sMC[row * SMC_LD + col] = (f16)acc1[nf][r];
            }
        }
        __syncthreads();

        // ===== score/softmax/comp: 32 thr/bond, 2 bond-passes, no spill =====
#pragma unroll 1
        for (int pass = 0; pass < 2; ++pass) {
            const int gb = pass * 32 + (tid >> 5);   // bond row in tile
            const int t5 = tid & 31;                 // lane within bond group
            int eg = e0 + gb; eg = eg < E_BONDS ? eg : E_BONDS - 1;

            int zero = 0;
            asm volatile("" : "+v"(zero));           // block LICM/CSE of gathers
            u32 nei[KNB][5];
#pragma unroll
            for (int k = 0; k < KNB; ++k) {
                int nb = bgraph[eg * KNB + k];
                const u32* p = (const u32*)msgIn + zero + (size_t)nb * (HP / 2) + t5 * 5;
#pragma unroll
                for (int j = 0; j < 5; ++j) nei[k][j] = p[j];
            }

            // ---- scores ----
            float pk[KNB] = {0.f, 0.f, 0.f, 0.f, 0.f, 0.f};
            const u32* mp = (const u32*)&sMC[gb * SMC_LD] + t5 * 5;
#pragma unroll
            for (int j = 0; j < 5; ++j) {
                u32 mtv = mp[j];
                float m0 = hlo(mtv), m1 = hhi(mtv);
#pragma unroll
                for (int k = 0; k < KNB; ++k)
                    pk[k] += hlo(nei[k][j]) * m0 + hhi(nei[k][j]) * m1;
            }
#pragma unroll
            for (int s = 1; s < 32; s <<= 1)
#pragma unroll
                for (int k = 0; k < KNB; ++k) pk[k] += __shfl_xor(pk[k], s);

            float mx = pk[0];
#pragma unroll
            for (int k = 1; k < KNB; ++k) mx = fmaxf(mx, pk[k]);
            float w[KNB], sum = 0.f;
#pragma unroll
            for (int k = 0; k < KNB; ++k) { w[k] = __expf(pk[k] - mx); sum += w[k]; }
            float inv = 1.f / sum;
#pragma unroll
            for (int k = 0; k < KNB; ++k) w[k] *= inv;

            // ---- comp (in-place over mt; own cells only) ----
            u32* cp = (u32*)&sMC[gb * SMC_LD] + t5 * 5;
#pragma unroll
            for (int j = 0; j < 5; ++j) {
                float c0 = 0.f, c1 = 0.f;
#pragma unroll
                for (int k = 0; k < KNB; ++k) {
                    c0 += w[k] * hlo(nei[k][j]);
                    c1 += w[k] * hhi(nei[k][j]);
                }
                cp[j] = packh2(c0, c1);
            }
        }
        __syncthreads();

        // ============ GEMM2: acc2 += comp_n @ WhT2_n ============
        const f16* B2 = WhT2 + (size_t)n * HP * HP;
        for (int kc = 0; kc < 5; ++kc) {
            __syncthreads();
            for (int wc = wv; wc < 40; wc += 16) {
                int q = wc * 64 + lane;
                int brow = q >> 3, c = q & 7;
                gl2lds16(B2 + (size_t)brow * HP + kc * 64 + ((c ^ (brow & 7)) << 3),
                         (char*)sB + wc * 1024);
            }
            __syncthreads();
#pragma unroll
            for (int lk = 0; lk < 2; ++lk) {
                int arow = wm * 16 + rl;
                f16x8 a  = *(const f16x8*)&sMC[arow * SMC_LD + kc * 64 + lk * 32 + cl * 8];
#pragma unroll
                for (int nf = 0; nf < 5; ++nf) {
                    int brow = (wn + nf * 4) * 16 + rl;
                    int bch  = (lk * 4 + cl) ^ (rl & 7);
                    f16x8 b  = *(const f16x8*)&sB[brow * 64 + bch * 8];
                    acc2[nf] = __builtin_amdgcn_mfma_f32_16x16x32_f16(a, b, acc2[nf], 0, 0, 0);
                }
            }
        }
        __syncthreads();   // protect sMC before next head's scatter
    }

    // ---- epilogue: msg_out = relu(binput + acc2) ----
#pragma unroll
    for (int nf = 0; nf < 5; ++nf) {
#pragma unroll
        for (int r = 0; r < 4; ++r) {
            int gm = e0 + wm * 16 + cl * 4 + r;
            if (gm >= E_BONDS) continue;
            int col = (wn + nf * 4) * 16 + rl;
            size_t ci = (size_t)gm * HP + col;
            float v = acc2[nf][r] + (float)binh[ci];
            msgOut[ci] = (f16)fmaxf(v, 0.f);
        }
    }
}

// ---------------------------------------------------------------------------
// a_nei[a] = sum_k msg[agraph[a][k]]
// ---------------------------------------------------------------------------
__global__ void gather_sum_h_k(const f16* __restrict__ msg,
                               const int* __restrict__ agraph,
                               f16* __restrict__ out) {
    int idx = blockIdx.x * 256 + threadIdx.x;
    if (idx >= NATOMS * (HP / 2)) return;
    int a = idx / (HP / 2), c = idx - a * (HP / 2);
    const int* g = agraph + (size_t)a * KNB;
    float s0 = 0.f, s1 = 0.f;
#pragma unroll
    for (int k = 0; k < KNB; ++k) {
        u32 u = *(const u32*)(msg + (size_t)g[k] * HP + c * 2);
        s0 += hlo(u); s1 += hhi(u);
    }
    ((u32*)out)[idx] = packh2(s0, s1);
}

// ---------------------------------------------------------------------------
__global__ void conv_pad_k(const float* __restrict__ src, f16* __restrict__ dst,
                           int R, int C, int CP) {
    int idx = blockIdx.x * 256 + threadIdx.x;
    if (idx >= R * CP) return;
    int r = idx / CP, c = idx - r * CP;
    dst[idx] = (f16)(c < C ? src[(size_t)r * C + c] : 0.f);
}

// ---------------------------------------------------------------------------
// Weight prep -> f16, padded, K-contiguous layouts.
// mode 0: WiT[320][192]   <- W_i[300][158]
// mode 1: WmaT[1280][320] <- row n*320+d, col h = W_ma[n][h][d]
// mode 2: WhT2[1280][320] <- row n*320+h, col d = W_h[h][n*300+d]
// mode 3: WoA[320][192]   <- W_o cols 0..143
// mode 4: WoB[320][320]   <- W_o cols 144..443
// else:   [320][320]      <- [300][300]
// ---------------------------------------------------------------------------
__global__ void prep_w_k(const float* __restrict__ src, f16* __restrict__ dst,
                         int mode, int R, int CK) {
    int idx = blockIdx.x * 256 + threadIdx.x;
    if (idx >= R * CK) return;
    int r = idx / CK, c = idx - r * CK;
    float v = 0.f;
    if (mode == 0) {
        if (r < HID && c < BONDIN) v = src[r * BONDIN + c];
    } else if (mode == 1) {
        int n = r / HP, d = r - n * HP;
        if (d < HID && c < HID) v = src[((size_t)n * HID + c) * HID + d];
    } else if (mode == 2) {
        int n = r / HP, h = r - n * HP;
        if (h < HID && c < HID) v = src[(size_t)h * (NH * HID) + n * HID + c];
    } else if (mode == 3) {
        if (r < HID && c < AFD) v = src[r * (AFD + HID) + c];
    } else if (mode == 4) {
        if (r < HID && c < HID) v = src[r * (AFD + HID) + AFD + c];
    } else {
        if (r < HID && c < HID) v = src[r * HID + c];
    }
    dst[idx] = (f16)v;
}

// ---------------------------------------------------------------------------
// MFMA molecule attention (unchanged from round 4).
// ---------------------------------------------------------------------------
__global__ __launch_bounds__(256) void mol_attn_mfma_k(
    const f16* __restrict__ atomHh,
    const f16* __restrict__ ah2h,
    f16* __restrict__ comp2h)
{
    __shared__ f16 sCur[64 * 320];
    __shared__ float sP[64][66];
    const int tid  = threadIdx.x;
    const int lane = tid & 63;
    const int wv   = tid >> 6;
    const int m    = blockIdx.x;
    const int rl   = lane & 15, cl = lane >> 4;

#pragma unroll
    for (int i = 0; i < 10; ++i) {
        int g   = i * 256 + wv * 64 + lane;
        int row = g / 40, c = g - row * 40;
        int grow = m * APM + row; grow = grow < NATOMS ? grow : NATOMS - 1;
        const f16* src = atomHh + (size_t)grow * HP + ((c ^ (row & 7)) << 3);
        gl2lds16(src, (char*)sCur + (size_t)(i * 256 + wv * 64) * 16);
    }
    __syncthreads();

    f32x4 acc[4];
#pragma unroll
    for (int nf = 0; nf < 4; ++nf) acc[nf] = (f32x4){0.f, 0.f, 0.f, 0.f};
    int qrow = m * APM + wv * 16 + rl;
    qrow = qrow < NATOMS ? qrow : NATOMS - 1;
    const f16* qbase = ah2h + (size_t)qrow * HP;
#pragma unroll
    for (int kh = 0; kh < 10; ++kh) {
        f16x8 aq = *(const f16x8*)(qbase + kh * 32 + cl * 8);
#pragma unroll
        for (int nf = 0; nf < 4; ++nf) {
            int brow = nf * 16 + rl;
            int ch   = (kh * 4 + cl) ^ (brow & 7);
            f16x8 bv = *(const f16x8*)&sCur[brow * 320 + ch * 8];
            acc[nf] = __builtin_amdgcn_mfma_f32_16x16x32_f16(aq, bv, acc[nf], 0, 0, 0);
        }
    }

#pragma unroll
    for (int r = 0; r < 4; ++r) {
        float s[4];
#pragma unroll
        for (int nf = 0; nf < 4; ++nf) {
            s[nf] = acc[nf][r];
            if (nf == 3 && rl >= 2) s[nf] = -1e30f;
        }
        float mx = fmaxf(fmaxf(s[0], s[1]), fmaxf(s[2], s[3]));
#pragma unroll
        for (int msk = 1; msk < 16; msk <<= 1) mx = fmaxf(mx, __shfl_xor(mx, msk));
        float e[4], sum = 0.f;
#pragma unroll
        for (int nf = 0; nf < 4; ++nf) { e[nf] = __expf(s[nf] - mx); sum += e[nf]; }
#pragma unroll
        for (int msk = 1; msk < 16; msk <<= 1) sum += __shfl_xor(sum, msk);
        float inv = 1.f / sum;
        int a = wv * 16 + cl * 4 + r;
#pragma unroll
        for (int nf = 0; nf < 4; ++nf) sP[a][nf * 16 + rl] = e[nf] * inv;
    }
    __syncthreads();

    const int a  = tid >> 2, hq = tid & 3;
    const bool aval = a < APM;
    const size_t orow = (size_t)(m * APM + a) * HP;
#pragma unroll
    for (int p = 0; p < 2; ++p) {
        float av[40];
#pragma unroll
        for (int i = 0; i < 40; ++i) av[i] = 0.f;
        const int ch0 = p * 20 + hq * 5;
        for (int b = 0; b < APM; ++b) {
            float w = sP[a][b];
#pragma unroll
            for (int i = 0; i < 5; ++i) {
                int ch = (ch0 + i) ^ (b & 7);
                f16x8 cv = *(const f16x8*)&sCur[b * 320 + ch * 8];
#pragma unroll
                for (int j = 0; j < 8; ++j) av[i * 8 + j] += w * (float)cv[j];
            }
        }
        if (aval) {
#pragma unroll
            for (int i = 0; i < 5; ++i) {
                f16x8 o;
#pragma unroll
                for (int j = 0; j < 8; ++j) o[j] = (f16)av[i * 8 + j];
                *(f16x8*)&comp2h[orow + p * 160 + hq * 40 + i * 8] = o;
            }
        }
    }
}

__global__ void mol_reduce_k(const float* __restrict__ atomH,
                             const float* __restrict__ atth,
                             float* __restrict__ out) {
    const int m = blockIdx.x;
    for (int h = threadIdx.x; h < HID; h += 256) {
        float s = 0.f;
        for (int a = 0; a < APM; ++a) {
            size_t i = (size_t)(m * APM + a) * HP + h;
            s += atomH[i] + atth[i];
        }
        out[(size_t)m * HID + h] = s * (1.f / APM);
    }
}

// ---------------------------------------------------------------------------
extern "C" void kernel_launch(void* const* d_in, const int* in_sizes, int n_in,
                              void* d_out, int out_size, void* d_ws, size_t ws_size,
                              hipStream_t stream) {
    const float* fatoms = (const float*)d_in[0];
    const float* fbonds = (const float*)d_in[1];
    const int*   agraph = (const int*)d_in[2];
    const int*   bgraph = (const int*)d_in[3];
    const float* W_i    = (const float*)d_in[4];
    const float* W_ma   = (const float*)d_in[5];
    const float* W_h    = (const float*)d_in[6];
    const float* W_o    = (const float*)d_in[7];
    const float* b_o    = (const float*)d_in[8];
    const float* W_a    = (const float*)d_in[9];
    const float* W_b    = (const float*)d_in[10];
    const float* b_b    = (const float*)d_in[11];
    float* out = (float*)d_out;

    // ---- workspace layout (max 213.7 MB) ----
    char* ws = (char*)d_ws;
    f16* msgA    = (f16*)(ws);                        // [60000][320]
    f16* msgB    = (f16*)(ws + 38400000);             // [60000][320]
    f16* binh    = (f16*)(ws + 76800000);             // [60000][320]
    f16* fbondsh = (f16*)(ws + 115200000);            // [60000][192] (pre-MP)
    // post-MP aliases:
    f16* aneih   = (f16*)(ws);                        // over msgA (dead)
    f16* fatomsh = (f16*)(ws + 38400000);             // over msgB (dead after gather)
    float* atomH = (float*)(ws + 76800000);           // over binh (dead)
    f16* atomHh  = (f16*)(ws + 115200000);
    f16* ah2h    = (f16*)(ws + 134400000);
    f16* comp2h  = (f16*)(ws + 153600000);
    float* atth  = (float*)(ws + 172800000);          // ends 211.2MB
    char* wb = ws + 211200000;
    f16* WiT  = (f16*)(wb);
    f16* WmaT = (f16*)(wb + 122880);
    f16* WhT2 = (f16*)(wb + 942080);
    f16* WoA  = (f16*)(wb + 1761280);
    f16* WoB  = (f16*)(wb + 1884160);
    f16* Wa   = (f16*)(wb + 2088960);
    f16* Wb   = (f16*)(wb + 2293760);

    // ---- weight/input prep ----
    prep_w_k<<<dim3((320 * 192 + 255) / 256), dim3(256), 0, stream>>>(W_i, WiT, 0, 320, 192);
    prep_w_k<<<dim3((1280 * 320 + 255) / 256), dim3(256), 0, stream>>>(W_ma, WmaT, 1, 1280, 320);
    prep_w_k<<<dim3((1280 * 320 + 255) / 256), dim3(256), 0, stream>>>(W_h, WhT2, 2, 1280, 320);
    prep_w_k<<<dim3((320 * 192 + 255) / 256), dim3(256), 0, stream>>>(W_o, WoA, 3, 320, 192);
    prep_w_k<<<dim3((320 * 320 + 255) / 256), dim3(256), 0, stream>>>(W_o, WoB, 4, 320, 320);
    prep_w_k<<<dim3((320 * 320 + 255) / 256), dim3(256), 0, stream>>>(W_a, Wa, 5, 320, 320);
    prep_w_k<<<dim3((320 * 320 + 255) / 256), dim3(256), 0, stream>>>(W_b, Wb, 6, 320, 320);
    conv_pad_k<<<dim3((E_BONDS * 192 + 255) / 256), dim3(256), 0, stream>>>(
        fbonds, fbondsh, E_BONDS, BONDIN, 192);

    // ---- binput/message0 ----
    mfma_gemm_k<128, 2><<<dim3(469, 3), dim3(256), 0, stream>>>(
        fbondsh, 192, WiT, 192, E_BONDS, 320, 192, HP, nullptr, binh, nullptr, nullptr, msgA);

    // ---- 3 fused message-passing iterations (ping-pong msgA <-> msgB) ----
    fused_mp_k<<<dim3(938), dim3(1024), 0, stream>>>(msgA, msgB, binh, bgraph, WmaT, WhT2);
    fused_mp_k<<<dim3(938), dim3(1024), 0, stream>>>(msgB, msgA, binh, bgraph, WmaT, WhT2);
    fused_mp_k<<<dim3(938), dim3(1024), 0, stream>>>(msgA, msgB, binh, bgraph, WmaT, WhT2);

    // ---- atom stage ----
    gather_sum_h_k<<<dim3((NATOMS * 160 + 255) / 256), dim3(256), 0, stream>>>(msgB, agraph, aneih);
    conv_pad_k<<<dim3((NATOMS * 192 + 255) / 256), dim3(256), 0, stream>>>(
        fatoms, fatomsh, NATOMS, AFD, 192);
    mfma_gemm_k<128, 0><<<dim3(235, 3), dim3(256), 0, stream>>>(
        fatomsh, 192, WoA, 192, NATOMS, 320, 192, HP, atomH, nullptr, nullptr, nullptr, nullptr);
    mfma_gemm_k<128, 4><<<dim3(235, 3), dim3(256), 0, stream>>>(
        aneih, HP, WoB, HP, NATOMS, 320, HP, HP, atomH, atomHh, b_o, nullptr, nullptr);

    // ---- molecule attention ----
    mfma_gemm_k<128, 1><<<dim3(235, 3), dim3(256), 0, stream>>>(
        atomHh, HP, Wa, HP, NATOMS, 320, HP, HP, nullptr, ah2h, nullptr, nullptr, nullptr);
    mol_attn_mfma_k<<<dim3(NMOLS), dim3(256), 0, stream>>>(atomHh, ah2h, comp2h);
    mfma_gemm_k<128, 5><<<dim3(235, 3), dim3(256), 0, stream>>>(
        comp2h, HP, Wb, HP, NATOMS, 320, HP, HP, atth, nullptr, b_b, nullptr, nullptr);
    mol_reduce_k<<<dim3(NMOLS), dim3(256), 0, stream>>>(atomH, atth, out);
}

// Round 8
// 1424.086 us; speedup vs baseline: 2.1722x; 1.4305x over previous
//
#include <hip/hip_runtime.h>
#include <hip/hip_bf16.h>
#include <math.h>

// Problem constants
#define HID       300
#define HP        320
#define NH        4
#define E_BONDS   60000
#define NATOMS    30000
#define KNB       6
#define NMOLS     600
#define APM       50
#define AFD       144
#define BONDIN    158

typedef unsigned short u16;
typedef unsigned int   u32;
typedef _Float16 f16;
typedef f16   f16x8 __attribute__((ext_vector_type(8)));
typedef float f32x4 __attribute__((ext_vector_type(4)));

// ---------------- helpers ----------------
__device__ inline float hlo(u32 u) { union { u32 i; f16 h[2]; } c; c.i = u; return (float)c.h[0]; }
__device__ inline float hhi(u32 u) { union { u32 i; f16 h[2]; } c; c.i = u; return (float)c.h[1]; }
__device__ inline u32 packh2(float a, float b) {
    union { u32 i; f16 h[2]; } c; c.h[0] = (f16)a; c.h[1] = (f16)b; return c.i;
}

__device__ inline void gl2lds16(const void* g, void* l) {
    __builtin_amdgcn_global_load_lds(
        (const __attribute__((address_space(1))) void*)g,
        (__attribute__((address_space(3))) void*)l, 16, 0, 0);
}

// ---------------------------------------------------------------------------
// MFMA GEMM (proven round 4): C = A[M][lda] @ B[Nb][ldb]^T, f16 in.
// EPI: 0 Cf=v | 1 Ch=h(v) | 2 Ch=h(v),out2=h(relu v) | 3 v+=resid,relu,Ch
//      4 v+=Cf+bias,relu,Cf&Ch | 5 v+=bias,relu,Cf
// ---------------------------------------------------------------------------
template <int BN, int EPI>
__global__ __launch_bounds__(256) void mfma_gemm_k(
    const f16* __restrict__ A, int lda,
    const f16* __restrict__ B, int ldb,
    int M, int Nb, int K, int ldc,
    float* __restrict__ Cf, f16* __restrict__ Ch,
    const float* __restrict__ bias,
    const f16* __restrict__ resid,
    f16* __restrict__ out2)
{
    constexpr int NF = BN / 32;
    __shared__ f16 sA[128 * 64];
    __shared__ f16 sB[BN * 64];
    const int tid  = threadIdx.x;
    const int lane = tid & 63;
    const int wv   = tid >> 6;
    const int wm   = wv >> 1, wn = wv & 1;
    const int m0   = blockIdx.x * 128, n0 = blockIdx.y * BN;

    f32x4 acc[4][NF];
#pragma unroll
    for (int i = 0; i < 4; ++i)
#pragma unroll
        for (int j = 0; j < NF; ++j) acc[i][j] = (f32x4){0.f, 0.f, 0.f, 0.f};

    for (int k0 = 0; k0 < K; k0 += 64) {
        __syncthreads();
#pragma unroll
        for (int i = 0; i < 4; ++i) {
            int o   = (((i * 4 + wv) * 64) + lane) * 16;
            int row = o >> 7;
            int p   = (o >> 4) & 7;
            int gr  = m0 + row; gr = gr < M ? gr : M - 1;
            const f16* g = A + (size_t)gr * lda + k0 + ((p ^ (row & 7)) << 3);
            gl2lds16(g, (char*)sA + (i * 4 + wv) * 1024);
        }
#pragma unroll
        for (int i = 0; i < BN / 32; ++i) {
            int o   = (((i * 4 + wv) * 64) + lane) * 16;
            int row = o >> 7;
            int p   = (o >> 4) & 7;
            int gr  = n0 + row; gr = gr < Nb ? gr : Nb - 1;
            const f16* g = B + (size_t)gr * ldb + k0 + ((p ^ (row & 7)) << 3);
            gl2lds16(g, (char*)sB + (i * 4 + wv) * 1024);
        }
        __syncthreads();

        const int rl = lane & 15, cl = lane >> 4;
#pragma unroll
        for (int kh = 0; kh < 2; ++kh) {
            f16x8 af[4], bfr[NF];
#pragma unroll
            for (int mf = 0; mf < 4; ++mf) {
                int row = wm * 64 + mf * 16 + rl;
                int ch  = (kh * 4 + cl) ^ (row & 7);
                af[mf]  = *(const f16x8*)&sA[row * 64 + ch * 8];
            }
#pragma unroll
            for (int nf = 0; nf < NF; ++nf) {
                int row = wn * (BN / 2) + nf * 16 + rl;
                int ch  = (kh * 4 + cl) ^ (row & 7);
                bfr[nf] = *(const f16x8*)&sB[row * 64 + ch * 8];
            }
#pragma unroll
            for (int mf = 0; mf < 4; ++mf)
#pragma unroll
                for (int nf = 0; nf < NF; ++nf)
                    acc[mf][nf] = __builtin_amdgcn_mfma_f32_16x16x32_f16(
                        af[mf], bfr[nf], acc[mf][nf], 0, 0, 0);
        }
    }

    const int rl = lane & 15, cl = lane >> 4;
#pragma unroll
    for (int mf = 0; mf < 4; ++mf) {
#pragma unroll
        for (int r = 0; r < 4; ++r) {
            int gm = m0 + wm * 64 + mf * 16 + cl * 4 + r;
            if (gm >= M) continue;
#pragma unroll
            for (int nf = 0; nf < NF; ++nf) {
                int gn = n0 + wn * (BN / 2) + nf * 16 + rl;
                if (gn >= ldc) continue;
                float v = acc[mf][nf][r];
                size_t ci = (size_t)gm * ldc + gn;
                if (EPI == 0) {
                    Cf[ci] = v;
                } else if (EPI == 1) {
                    Ch[ci] = (f16)v;
                } else if (EPI == 2) {
                    Ch[ci] = (f16)v;
                    out2[ci] = (f16)fmaxf(v, 0.f);
                } else if (EPI == 3) {
                    v += (float)resid[ci];
                    Ch[ci] = (f16)fmaxf(v, 0.f);
                } else if (EPI == 4) {
                    v += Cf[ci];
                    v += (gn < HID) ? bias[gn] : 0.f;
                    v = fmaxf(v, 0.f);
                    Cf[ci] = v; Ch[ci] = (f16)v;
                } else {
                    v += (gn < HID) ? bias[gn] : 0.f;
                    Cf[ci] = fmaxf(v, 0.f);
                }
            }
        }
    }
}

// ---------------------------------------------------------------------------
// FUSED message-passing iteration (v4 — 512 thr / 8 waves / 2 waves-per-SIMD
// => 256-reg budget on the unified file; no spill by construction).
// Per head: GEMM1 (mt = sMsg @ WmaT_n) -> sMC; score/softmax/comp with
// 16 thr/bond x 2 passes (nei[6][10]=60 VGPR transient); GEMM2 partial
// (acc2 += comp @ WhT2_n). Epilogue relu(binput + acc2).
// Wave grid 2m x 4n: wave tile 32 rows x 80 cols; acc [2][5] f32x4.
// ---------------------------------------------------------------------------
#define SMC_LD 328   // 320 + 8 pad

__global__ __launch_bounds__(512, 2) void fused_mp_k(
    const f16* __restrict__ msgIn,   // [E][320]
    f16* __restrict__ msgOut,        // [E][320]
    const f16* __restrict__ binh,    // [E][320]
    const int* __restrict__ bgraph,  // [E][6]
    const f16* __restrict__ WmaT,    // [4*320][320]  row n*320+d, col h
    const f16* __restrict__ WhT2)    // [4*320][320]  row n*320+h, col d
{
    __shared__ f16 sMsg[64 * 320];        // 40 KB, XOR-swizzled 16B chunks
    __shared__ f16 sMC[64 * SMC_LD];      // 41 KB, mt/comp (padded rows)
    __shared__ f16 sB[320 * 64];          // 40 KB, weight k-chunk (swizzled)

    const int tid  = threadIdx.x;
    const int lane = tid & 63;
    const int wv   = tid >> 6;            // 0..7
    const int wm   = wv >> 2;             // 0..1
    const int wn   = wv & 3;              // 0..3
    const int rl   = lane & 15, cl = lane >> 4;
    const int e0   = blockIdx.x * 64;

    // ---- stage sMsg: 2560 16B-chunks (40 per row), wave-uniform dests ----
    for (int wc = wv; wc < 40; wc += 8) {
        int q   = wc * 64 + lane;
        int row = q / 40, c = q - row * 40;
        int gr  = e0 + row; gr = gr < E_BONDS ? gr : E_BONDS - 1;
        gl2lds16(msgIn + (size_t)gr * HP + ((c ^ (row & 7)) << 3),
                 (char*)sMsg + wc * 1024);
    }
    __syncthreads();

    f32x4 acc2[2][5];
#pragma unroll
    for (int mf = 0; mf < 2; ++mf)
#pragma unroll
        for (int nf = 0; nf < 5; ++nf) acc2[mf][nf] = (f32x4){0.f, 0.f, 0.f, 0.f};

#pragma unroll 1
    for (int n = 0; n < NH; ++n) {
        // ================= GEMM1: mt_n = sMsg @ WmaT_n =================
        const f16* B1 = WmaT + (size_t)n * HP * HP;
        f32x4 acc1[2][5];
#pragma unroll
        for (int mf = 0; mf < 2; ++mf)
#pragma unroll
            for (int nf = 0; nf < 5; ++nf) acc1[mf][nf] = (f32x4){0.f, 0.f, 0.f, 0.f};

        for (int kc = 0; kc < 5; ++kc) {
            __syncthreads();
            for (int wc = wv; wc < 40; wc += 8) {
                int q = wc * 64 + lane;
                int brow = q >> 3, c = q & 7;
                gl2lds16(B1 + (size_t)brow * HP + kc * 64 + ((c ^ (brow & 7)) << 3),
                         (char*)sB + wc * 1024);
            }
            __syncthreads();
#pragma unroll
            for (int lk = 0; lk < 2; ++lk) {
                f16x8 a[2];
#pragma unroll
                for (int mf = 0; mf < 2; ++mf) {
                    int arow = wm * 32 + mf * 16 + rl;
                    int ach  = (kc * 8 + lk * 4 + cl) ^ (rl & 7);
                    a[mf] = *(const f16x8*)&sMsg[arow * HP + ach * 8];
                }
#pragma unroll
                for (int nf = 0; nf < 5; ++nf) {
                    int brow = (wn + nf * 4) * 16 + rl;
                    int bch  = (lk * 4 + cl) ^ (rl & 7);
                    f16x8 b  = *(const f16x8*)&sB[brow * 64 + bch * 8];
                    acc1[0][nf] = __builtin_amdgcn_mfma_f32_16x16x32_f16(a[0], b, acc1[0][nf], 0, 0, 0);
                    acc1[1][nf] = __builtin_amdgcn_mfma_f32_16x16x32_f16(a[1], b, acc1[1][nf], 0, 0, 0);
                }
            }
        }
        // scatter mt to sMC
#pragma unroll
        for (int mf = 0; mf < 2; ++mf)
#pragma unroll
            for (int nf = 0; nf < 5; ++nf) {
#pragma unroll
                for (int r = 0; r < 4; ++r) {
                    int row = wm * 32 + mf * 16 + cl * 4 + r;
                    int col = (wn + nf * 4) * 16 + rl;
                    sMC[row * SMC_LD + col] = (f16)acc1[mf][nf][r];
                }
            }
        __syncthreads();

        // ===== score/softmax/comp: 16 thr/bond, 2 bond-passes =====
#pragma unroll 1
        for (int pass = 0; pass < 2; ++pass) {
            const int gb = pass * 32 + (tid >> 4);   // bond row in tile
            const int t  = tid & 15;                 // lane within bond group
            int eg = e0 + gb; eg = eg < E_BONDS ? eg : E_BONDS - 1;

            int zero = 0;
            asm volatile("" : "+v"(zero));           // block LICM/CSE of gathers
            u32 nei[KNB][10];
#pragma unroll
            for (int k = 0; k < KNB; ++k) {
                int nb = bgraph[eg * KNB + k];
                const u32* p = (const u32*)msgIn + zero + (size_t)nb * (HP / 2) + t * 10;
#pragma unroll
                for (int j = 0; j < 10; ++j) nei[k][j] = p[j];
            }

            // ---- scores ----
            float pk[KNB] = {0.f, 0.f, 0.f, 0.f, 0.f, 0.f};
            const u32* mp = (const u32*)&sMC[gb * SMC_LD] + t * 10;
#pragma unroll
            for (int j = 0; j < 10; ++j) {
                u32 mtv = mp[j];
                float m0 = hlo(mtv), m1 = hhi(mtv);
#pragma unroll
                for (int k = 0; k < KNB; ++k)
                    pk[k] += hlo(nei[k][j]) * m0 + hhi(nei[k][j]) * m1;
            }
#pragma unroll
            for (int s = 1; s < 16; s <<= 1)
#pragma unroll
                for (int k = 0; k < KNB; ++k) pk[k] += __shfl_xor(pk[k], s);

            float mx = pk[0];
#pragma unroll
            for (int k = 1; k < KNB; ++k) mx = fmaxf(mx, pk[k]);
            float w[KNB], sum = 0.f;
#pragma unroll
            for (int k = 0; k < KNB; ++k) { w[k] = __expf(pk[k] - mx); sum += w[k]; }
            float inv = 1.f / sum;
#pragma unroll
            for (int k = 0; k < KNB; ++k) w[k] *= inv;

            // ---- comp (in-place over mt; own cells only) ----
            u32* cp = (u32*)&sMC[gb * SMC_LD] + t * 10;
#pragma unroll
            for (int j = 0; j < 10; ++j) {
                float c0 = 0.f, c1 = 0.f;
#pragma unroll
                for (int k = 0; k < KNB; ++k) {
                    c0 += w[k] * hlo(nei[k][j]);
                    c1 += w[k] * hhi(nei[k][j]);
                }
                cp[j] = packh2(c0, c1);
            }
        }
        __syncthreads();

        // ============ GEMM2: acc2 += comp_n @ WhT2_n ============
        const f16* B2 = WhT2 + (size_t)n * HP * HP;
        for (int kc = 0; kc < 5; ++kc) {
            __syncthreads();
            for (int wc = wv; wc < 40; wc += 8) {
                int q = wc * 64 + lane;
                int brow = q >> 3, c = q & 7;
                gl2lds16(B2 + (size_t)brow * HP + kc * 64 + ((c ^ (brow & 7)) << 3),
                         (char*)sB + wc * 1024);
            }
            __syncthreads();
#pragma unroll
            for (int lk = 0; lk < 2; ++lk) {
                f16x8 a[2];
#pragma unroll
                for (int mf = 0; mf < 2; ++mf) {
                    int arow = wm * 32 + mf * 16 + rl;
                    a[mf] = *(const f16x8*)&sMC[arow * SMC_LD + kc * 64 + lk * 32 + cl * 8];
                }
#pragma unroll
                for (int nf = 0; nf < 5; ++nf) {
                    int brow = (wn + nf * 4) * 16 + rl;
                    int bch  = (lk * 4 + cl) ^ (rl & 7);
                    f16x8 b  = *(const f16x8*)&sB[brow * 64 + bch * 8];
                    acc2[0][nf] = __builtin_amdgcn_mfma_f32_16x16x32_f16(a[0], b, acc2[0][nf], 0, 0, 0);
                    acc2[1][nf] = __builtin_amdgcn_mfma_f32_16x16x32_f16(a[1], b, acc2[1][nf], 0, 0, 0);
                }
            }
        }
        __syncthreads();   // protect sMC before next head's scatter
    }

    // ---- epilogue: msg_out = relu(binput + acc2) ----
#pragma unroll
    for (int mf = 0; mf < 2; ++mf)
#pragma unroll
        for (int nf = 0; nf < 5; ++nf) {
#pragma unroll
            for (int r = 0; r < 4; ++r) {
                int gm = e0 + wm * 32 + mf * 16 + cl * 4 + r;
                if (gm >= E_BONDS) continue;
                int col = (wn + nf * 4) * 16 + rl;
                size_t ci = (size_t)gm * HP + col;
                float v = acc2[mf][nf][r] + (float)binh[ci];
                msgOut[ci] = (f16)fmaxf(v, 0.f);
            }
        }
}

// ---------------------------------------------------------------------------
// a_nei[a] = sum_k msg[agraph[a][k]]
// ---------------------------------------------------------------------------
__global__ void gather_sum_h_k(const f16* __restrict__ msg,
                               const int* __restrict__ agraph,
                               f16* __restrict__ out) {
    int idx = blockIdx.x * 256 + threadIdx.x;
    if (idx >= NATOMS * (HP / 2)) return;
    int a = idx / (HP / 2), c = idx - a * (HP / 2);
    const int* g = agraph + (size_t)a * KNB;
    float s0 = 0.f, s1 = 0.f;
#pragma unroll
    for (int k = 0; k < KNB; ++k) {
        u32 u = *(const u32*)(msg + (size_t)g[k] * HP + c * 2);
        s0 += hlo(u); s1 += hhi(u);
    }
    ((u32*)out)[idx] = packh2(s0, s1);
}

// ---------------------------------------------------------------------------
__global__ void conv_pad_k(const float* __restrict__ src, f16* __restrict__ dst,
                           int R, int C, int CP) {
    int idx = blockIdx.x * 256 + threadIdx.x;
    if (idx >= R * CP) return;
    int r = idx / CP, c = idx - r * CP;
    dst[idx] = (f16)(c < C ? src[(size_t)r * C + c] : 0.f);
}

// ---------------------------------------------------------------------------
// Weight prep -> f16, padded, K-contiguous layouts.
// mode 0: WiT[320][192]   <- W_i[300][158]
// mode 1: WmaT[1280][320] <- row n*320+d, col h = W_ma[n][h][d]
// mode 2: WhT2[1280][320] <- row n*320+h, col d = W_h[h][n*300+d]
// mode 3: WoA[320][192]   <- W_o cols 0..143
// mode 4: WoB[320][320]   <- W_o cols 144..443
// else:   [320][320]      <- [300][300]
// ---------------------------------------------------------------------------
__global__ void prep_w_k(const float* __restrict__ src, f16* __restrict__ dst,
                         int mode, int R, int CK) {
    int idx = blockIdx.x * 256 + threadIdx.x;
    if (idx >= R * CK) return;
    int r = idx / CK, c = idx - r * CK;
    float v = 0.f;
    if (mode == 0) {
        if (r < HID && c < BONDIN) v = src[r * BONDIN + c];
    } else if (mode == 1) {
        int n = r / HP, d = r - n * HP;
        if (d < HID && c < HID) v = src[((size_t)n * HID + c) * HID + d];
    } else if (mode == 2) {
        int n = r / HP, h = r - n * HP;
        if (h < HID && c < HID) v = src[(size_t)h * (NH * HID) + n * HID + c];
    } else if (mode == 3) {
        if (r < HID && c < AFD) v = src[r * (AFD + HID) + c];
    } else if (mode == 4) {
        if (r < HID && c < HID) v = src[r * (AFD + HID) + AFD + c];
    } else {
        if (r < HID && c < HID) v = src[r * HID + c];
    }
    dst[idx] = (f16)v;
}

// ---------------------------------------------------------------------------
// MFMA molecule attention (unchanged from round 4).
// ---------------------------------------------------------------------------
__global__ __launch_bounds__(256) void mol_attn_mfma_k(
    const f16* __restrict__ atomHh,
    const f16* __restrict__ ah2h,
    f16* __restrict__ comp2h)
{
    __shared__ f16 sCur[64 * 320];
    __shared__ float sP[64][66];
    const int tid  = threadIdx.x;
    const int lane = tid & 63;
    const int wv   = tid >> 6;
    const int m    = blockIdx.x;
    const int rl   = lane & 15, cl = lane >> 4;

#pragma unroll
    for (int i = 0; i < 10; ++i) {
        int g   = i * 256 + wv * 64 + lane;
        int row = g / 40, c = g - row * 40;
        int grow = m * APM + row; grow = grow < NATOMS ? grow : NATOMS - 1;
        const f16* src = atomHh + (size_t)grow * HP + ((c ^ (row & 7)) << 3);
        gl2lds16(src, (char*)sCur + (size_t)(i * 256 + wv * 64) * 16);
    }
    __syncthreads();

    f32x4 acc[4];
#pragma unroll
    for (int nf = 0; nf < 4; ++nf) acc[nf] = (f32x4){0.f, 0.f, 0.f, 0.f};
    int qrow = m * APM + wv * 16 + rl;
    qrow = qrow < NATOMS ? qrow : NATOMS - 1;
    const f16* qbase = ah2h + (size_t)qrow * HP;
#pragma unroll
    for (int kh = 0; kh < 10; ++kh) {
        f16x8 aq = *(const f16x8*)(qbase + kh * 32 + cl * 8);
#pragma unroll
        for (int nf = 0; nf < 4; ++nf) {
            int brow = nf * 16 + rl;
            int ch   = (kh * 4 + cl) ^ (brow & 7);
            f16x8 bv = *(const f16x8*)&sCur[brow * 320 + ch * 8];
            acc[nf] = __builtin_amdgcn_mfma_f32_16x16x32_f16(aq, bv, acc[nf], 0, 0, 0);
        }
    }

#pragma unroll
    for (int r = 0; r < 4; ++r) {
        float s[4];
#pragma unroll
        for (int nf = 0; nf < 4; ++nf) {
            s[nf] = acc[nf][r];
            if (nf == 3 && rl >= 2) s[nf] = -1e30f;
        }
        float mx = fmaxf(fmaxf(s[0], s[1]), fmaxf(s[2], s[3]));
#pragma unroll
        for (int msk = 1; msk < 16; msk <<= 1) mx = fmaxf(mx, __shfl_xor(mx, msk));
        float e[4], sum = 0.f;
#pragma unroll
        for (int nf = 0; nf < 4; ++nf) { e[nf] = __expf(s[nf] - mx); sum += e[nf]; }
#pragma unroll
        for (int msk = 1; msk < 16; msk <<= 1) sum += __shfl_xor(sum, msk);
        float inv = 1.f / sum;
        int a = wv * 16 + cl * 4 + r;
#pragma unroll
        for (int nf = 0; nf < 4; ++nf) sP[a][nf * 16 + rl] = e[nf] * inv;
    }
    __syncthreads();

    const int a  = tid >> 2, hq = tid & 3;
    const bool aval = a < APM;
    const size_t orow = (size_t)(m * APM + a) * HP;
#pragma unroll
    for (int p = 0; p < 2; ++p) {
        float av[40];
#pragma unroll
        for (int i = 0; i < 40; ++i) av[i] = 0.f;
        const int ch0 = p * 20 + hq * 5;
        for (int b = 0; b < APM; ++b) {
            float w = sP[a][b];
#pragma unroll
            for (int i = 0; i < 5; ++i) {
                int ch = (ch0 + i) ^ (b & 7);
                f16x8 cv = *(const f16x8*)&sCur[b * 320 + ch * 8];
#pragma unroll
                for (int j = 0; j < 8; ++j) av[i * 8 + j] += w * (float)cv[j];
            }
        }
        if (aval) {
#pragma unroll
            for (int i = 0; i < 5; ++i) {
                f16x8 o;
#pragma unroll
                for (int j = 0; j < 8; ++j) o[j] = (f16)av[i * 8 + j];
                *(f16x8*)&comp2h[orow + p * 160 + hq * 40 + i * 8] = o;
            }
        }
    }
}

__global__ void mol_reduce_k(const float* __restrict__ atomH,
                             const float* __restrict__ atth,
                             float* __restrict__ out) {
    const int m = blockIdx.x;
    for (int h = threadIdx.x; h < HID; h += 256) {
        float s = 0.f;
        for (int a = 0; a < APM; ++a) {
            size_t i = (size_t)(m * APM + a) * HP + h;
            s += atomH[i] + atth[i];
        }
        out[(size_t)m * HID + h] = s * (1.f / APM);
    }
}

// ---------------------------------------------------------------------------
extern "C" void kernel_launch(void* const* d_in, const int* in_sizes, int n_in,
                              void* d_out, int out_size, void* d_ws, size_t ws_size,
                              hipStream_t stream) {
    const float* fatoms = (const float*)d_in[0];
    const float* fbonds = (const float*)d_in[1];
    const int*   agraph = (const int*)d_in[2];
    const int*   bgraph = (const int*)d_in[3];
    const float* W_i    = (const float*)d_in[4];
    const float* W_ma   = (const float*)d_in[5];
    const float* W_h    = (const float*)d_in[6];
    const float* W_o    = (const float*)d_in[7];
    const float* b_o    = (const float*)d_in[8];
    const float* W_a    = (const float*)d_in[9];
    const float* W_b    = (const float*)d_in[10];
    const float* b_b    = (const float*)d_in[11];
    float* out = (float*)d_out;

    // ---- workspace layout (max 213.7 MB) ----
    char* ws = (char*)d_ws;
    f16* msgA    = (f16*)(ws);                        // [60000][320]
    f16* msgB    = (f16*)(ws + 38400000);             // [60000][320]
    f16* binh    = (f16*)(ws + 76800000);             // [60000][320]
    f16* fbondsh = (f16*)(ws + 115200000);            // [60000][192] (pre-MP)
    // post-MP aliases:
    f16* aneih   = (f16*)(ws);                        // over msgA (dead)
    f16* fatomsh = (f16*)(ws + 38400000);             // over msgB (dead after gather)
    float* atomH = (float*)(ws + 76800000);           // over binh (dead)
    f16* atomHh  = (f16*)(ws + 115200000);
    f16* ah2h    = (f16*)(ws + 134400000);
    f16* comp2h  = (f16*)(ws + 153600000);
    float* atth  = (float*)(ws + 172800000);          // ends 211.2MB
    char* wb = ws + 211200000;
    f16* WiT  = (f16*)(wb);
    f16* WmaT = (f16*)(wb + 122880);
    f16* WhT2 = (f16*)(wb + 942080);
    f16* WoA  = (f16*)(wb + 1761280);
    f16* WoB  = (f16*)(wb + 1884160);
    f16* Wa   = (f16*)(wb + 2088960);
    f16* Wb   = (f16*)(wb + 2293760);

    // ---- weight/input prep ----
    prep_w_k<<<dim3((320 * 192 + 255) / 256), dim3(256), 0, stream>>>(W_i, WiT, 0, 320, 192);
    prep_w_k<<<dim3((1280 * 320 + 255) / 256), dim3(256), 0, stream>>>(W_ma, WmaT, 1, 1280, 320);
    prep_w_k<<<dim3((1280 * 320 + 255) / 256), dim3(256), 0, stream>>>(W_h, WhT2, 2, 1280, 320);
    prep_w_k<<<dim3((320 * 192 + 255) / 256), dim3(256), 0, stream>>>(W_o, WoA, 3, 320, 192);
    prep_w_k<<<dim3((320 * 320 + 255) / 256), dim3(256), 0, stream>>>(W_o, WoB, 4, 320, 320);
    prep_w_k<<<dim3((320 * 320 + 255) / 256), dim3(256), 0, stream>>>(W_a, Wa, 5, 320, 320);
    prep_w_k<<<dim3((320 * 320 + 255) / 256), dim3(256), 0, stream>>>(W_b, Wb, 6, 320, 320);
    conv_pad_k<<<dim3((E_BONDS * 192 + 255) / 256), dim3(256), 0, stream>>>(
        fbonds, fbondsh, E_BONDS, BONDIN, 192);

    // ---- binput/message0 ----
    mfma_gemm_k<128, 2><<<dim3(469, 3), dim3(256), 0, stream>>>(
        fbondsh, 192, WiT, 192, E_BONDS, 320, 192, HP, nullptr, binh, nullptr, nullptr, msgA);

    // ---- 3 fused message-passing iterations (ping-pong msgA <-> msgB) ----
    fused_mp_k<<<dim3(938), dim3(512), 0, stream>>>(msgA, msgB, binh, bgraph, WmaT, WhT2);
    fused_mp_k<<<dim3(938), dim3(512), 0, stream>>>(msgB, msgA, binh, bgraph, WmaT, WhT2);
    fused_mp_k<<<dim3(938), dim3(512), 0, stream>>>(msgA, msgB, binh, bgraph, WmaT, WhT2);

    // ---- atom stage ----
    gather_sum_h_k<<<dim3((NATOMS * 160 + 255) / 256), dim3(256), 0, stream>>>(msgB, agraph, aneih);
    conv_pad_k<<<dim3((NATOMS * 192 + 255) / 256), dim3(256), 0, stream>>>(
        fatoms, fatomsh, NATOMS, AFD, 192);
    mfma_gemm_k<128, 0><<<dim3(235, 3), dim3(256), 0, stream>>>(
        fatomsh, 192, WoA, 192, NATOMS, 320, 192, HP, atomH, nullptr, nullptr, nullptr, nullptr);
    mfma_gemm_k<128, 4><<<dim3(235, 3), dim3(256), 0, stream>>>(
        aneih, HP, WoB, HP, NATOMS, 320, HP, HP, atomH, atomHh, b_o, nullptr, nullptr);

    // ---- molecule attention ----
    mfma_gemm_k<128, 1><<<dim3(235, 3), dim3(256), 0, stream>>>(
        atomHh, HP, Wa, HP, NATOMS, 320, HP, HP, nullptr, ah2h, nullptr, nullptr, nullptr);
    mol_attn_mfma_k<<<dim3(NMOLS), dim3(256), 0, stream>>>(atomHh, ah2h, comp2h);
    mfma_gemm_k<128, 5><<<dim3(235, 3), dim3(256), 0, stream>>>(
        comp2h, HP, Wb, HP, NATOMS, 320, HP, HP, atth, nullptr, b_b, nullptr, nullptr);
    mol_reduce_k<<<dim3(NMOLS), dim3(256), 0, stream>>>(atomH, atth, out);
}